// Round 22
// baseline (993.180 us; speedup 1.0000x reference)
//
#include <hip/hip_runtime.h>
#include <stdint.h>

#define CONF_T 0.05f
#define NMS_T  0.5f
#define WMAX   132           // ceil(8400/64)
#define WSTEP9 589824        // 256*256*9

typedef _Float16 f16x8 __attribute__((ext_vector_type(8)));
typedef _Float16 f16x2 __attribute__((ext_vector_type(2)));
typedef float    f32x4 __attribute__((ext_vector_type(4)));
#define MFMA16 __builtin_amdgcn_mfma_f32_16x16x32_f16

// ---- workspace layout (float offsets) ----
#define OFF_T3   0u
#define OFF_T4   1638400u
#define OFF_T5   2048000u
#define OFF_P3   2150400u
#define OFF_P4   3788800u
#define OFF_P5   4198400u
#define OFF_HA3  4300800u
#define OFF_HA4  5939200u
#define OFF_HA5  6348800u
#define OFF_HB3  6451200u
#define OFF_HB4  8089600u
#define OFF_HB5  8499200u
#define OFF_HD3  8601600u
#define OFF_HD4  10240000u
#define OFF_HD5  10649600u
#define OFF_CLS  10752000u
#define OFF_REG  11424000u
#define OFF_CTN  11457600u
#define OFF_W2H  11466000u                 // 11 matrices x 589824 f16 (hi)
#define OFF_W2L  14710032u                 // (lo)
#define WS_NEED  17954064u
// post-processing arrays (T3 region, free after conv stack)
#define POFF_KEYS  (OFF_T3 + 0u)
#define POFF_SCS   (OFF_T3 + 32768u)
#define POFF_CLSS  (OFF_T3 + 49152u)
#define POFF_IDXS  (OFF_T3 + 65536u)
#define POFF_GX1   (OFF_T3 + 81920u)
#define POFF_GY1   (OFF_T3 + 90320u)
#define POFF_GX2   (OFF_T3 + 98720u)
#define POFF_GY2   (OFF_T3 + 107120u)
#define POFF_GAR   (OFF_T3 + 115520u)
#define POFF_GIX   (OFF_T3 + 123920u)
#define POFF_NCNT  (OFF_T3 + 132320u)
#define POFF_NBASE (OFF_T3 + 132400u)
#define POFF_CROW  (OFF_T3 + 132480u)      // 8400 ints: compacted row -> class
#define POFF_NZ    (OFF_T3 + 140880u)      // 8400 x 4 u64 nonzero-word bitmaps
#define POFF_MASK  OFF_HA3

// ---------------- conv 1x1 (+ optional nearest-up2 add) ----------------
__launch_bounds__(256)
__global__ void conv1x1_kernel(const float* __restrict__ in, const float* __restrict__ w,
                               const float* __restrict__ b, float* __restrict__ out,
                               const float* __restrict__ add,
                               int Cin, int Cout, int NPX, int W, int outStride, int outBase)
{
    __shared__ float s_in[16][64];
    __shared__ float s_w[16][64];
    int t = threadIdx.x;
    int pxg = t & 31, cg = t >> 5;
    int px0 = blockIdx.x * 64;
    int co0 = blockIdx.y * 64;
    float acc[8][2];
#pragma unroll
    for (int c = 0; c < 8; ++c) { acc[c][0] = 0.f; acc[c][1] = 0.f; }
    int chunks = Cin >> 4;
    int wco = t >> 2, wpart = t & 3;
    for (int ch = 0; ch < chunks; ++ch) {
        int ci0 = ch << 4;
#pragma unroll
        for (int k = 0; k < 4; ++k) {
            int id = t + k * 256;
            int ci = id >> 6, pp = id & 63;
            int gp = px0 + pp;
            s_in[ci][pp] = (gp < NPX) ? in[(size_t)(ci0 + ci) * NPX + gp] : 0.f;
        }
        {
            int gco = co0 + wco;
            if (gco < Cout) {
                const float* run = w + (size_t)gco * Cin + ci0;
#pragma unroll
                for (int k = 0; k < 4; ++k) {
                    int e = wpart + 4 * k;
                    s_w[e][wco] = run[e];
                }
            } else {
#pragma unroll
                for (int k = 0; k < 4; ++k) s_w[wpart + 4 * k][wco] = 0.f;
            }
        }
        __syncthreads();
#pragma unroll
        for (int ci = 0; ci < 16; ++ci) {
            float i0 = s_in[ci][pxg * 2], i1 = s_in[ci][pxg * 2 + 1];
#pragma unroll
            for (int c = 0; c < 8; ++c) {
                float wv = s_w[ci][cg * 8 + c];
                acc[c][0] += wv * i0;
                acc[c][1] += wv * i1;
            }
        }
        __syncthreads();
    }
    for (int c = 0; c < 8; ++c) {
        int co = co0 + cg * 8 + c;
        if (co >= Cout) break;
        float bb = b[co];
#pragma unroll
        for (int j = 0; j < 2; ++j) {
            int p = px0 + pxg * 2 + j;
            if (p < NPX) {
                float v = acc[c][j] + bb;
                if (add) {
                    int y = p / W, x = p % W;
                    int Sp = W >> 1;
                    v += add[(size_t)co * (Sp * Sp) + (y >> 1) * Sp + (x >> 1)];
                }
                out[(size_t)co * outStride + outBase + p] = v;
            }
        }
    }
}

// ---------------- fused detector 1x1 (9 combos in one dispatch) ----------------
struct Det9 {
    const float* src[9]; const float* w[9]; const float* b[9];
    float*       dst[9];
    int cout[9], npx[9], obase[9], bstart[9], npxb[9];
};

__launch_bounds__(256)
__global__ void det1x1_fused(Det9 d)
{
    int bid = blockIdx.x;
    int q = 0;
#pragma unroll
    for (int i = 1; i < 9; ++i) if (bid >= d.bstart[i]) q = i;
    int local = bid - d.bstart[q];
    int coIdx = local / d.npxb[q];
    int pxIdx = local - coIdx * d.npxb[q];
    const float* in = d.src[q];
    const float* w  = d.w[q];
    const float* b  = d.b[q];
    float* out = d.dst[q];
    int Cout = d.cout[q], NPX = d.npx[q], outBase = d.obase[q];

    __shared__ float s_in[16][64];
    __shared__ float s_w[16][64];
    int t = threadIdx.x;
    int pxg = t & 31, cg = t >> 5;
    int px0 = pxIdx * 64;
    int co0 = coIdx * 64;
    float acc[8][2];
#pragma unroll
    for (int c = 0; c < 8; ++c) { acc[c][0] = 0.f; acc[c][1] = 0.f; }
    int wco = t >> 2, wpart = t & 3;
    for (int ch = 0; ch < 16; ++ch) {
        int ci0 = ch << 4;
#pragma unroll
        for (int k = 0; k < 4; ++k) {
            int id = t + k * 256;
            int ci = id >> 6, pp = id & 63;
            int gp = px0 + pp;
            s_in[ci][pp] = (gp < NPX) ? in[(size_t)(ci0 + ci) * NPX + gp] : 0.f;
        }
        {
            int gco = co0 + wco;
            if (gco < Cout) {
                const float* run = w + (size_t)gco * 256 + ci0;
#pragma unroll
                for (int k = 0; k < 4; ++k) {
                    int e = wpart + 4 * k;
                    s_w[e][wco] = run[e];
                }
            } else {
#pragma unroll
                for (int k = 0; k < 4; ++k) s_w[wpart + 4 * k][wco] = 0.f;
            }
        }
        __syncthreads();
#pragma unroll
        for (int ci = 0; ci < 16; ++ci) {
            float i0 = s_in[ci][pxg * 2], i1 = s_in[ci][pxg * 2 + 1];
#pragma unroll
            for (int c = 0; c < 8; ++c) {
                float wv = s_w[ci][cg * 8 + c];
                acc[c][0] += wv * i0;
                acc[c][1] += wv * i1;
            }
        }
        __syncthreads();
    }
    for (int c = 0; c < 8; ++c) {
        int co = co0 + cg * 8 + c;
        if (co >= Cout) break;
        float bb = b[co];
#pragma unroll
        for (int j = 0; j < 2; ++j) {
            int p = px0 + pxg * 2 + j;
            if (p < NPX) out[(size_t)co * 8400 + outBase + p] = acc[c][j] + bb;
        }
    }
}

// ---------------- MFMA path: weight f16 hi/lo prep (FRAGMENT-ORDER layout) ----
__launch_bounds__(256)
__global__ void w2prep(const float* __restrict__ clsh_w, const float* __restrict__ regh_w,
                       const float* __restrict__ sm1_w, const float* __restrict__ sm2_w,
                       const float* __restrict__ sm3_w,
                       _Float16* __restrict__ WH, _Float16* __restrict__ WL)
{
    int idx = blockIdx.x * 256 + threadIdx.x;
    if (idx >= 11 * WSTEP9) return;
    int m = idx / WSTEP9, e = idx - m * WSTEP9;
    int tap = e / 65536;            // 16 cob * 8 ck * 512
    int r   = e - tap * 65536;
    int cob = r / 4096;             // 8 ck * 512
    int r2  = r - cob * 4096;
    int ck  = r2 / 512;
    int r3  = r2 - ck * 512;
    int lane = r3 / 8, el = r3 - (r3 / 8) * 8;
    int co = cob * 16 + (lane & 15);
    int ci = ck * 32 + (lane >> 4) * 8 + el;
    const float* srcb;
    if (m < 4)       srcb = clsh_w + (size_t)m * WSTEP9;
    else if (m < 8)  srcb = regh_w + (size_t)(m - 4) * WSTEP9;
    else if (m == 8) srcb = sm1_w;
    else if (m == 9) srcb = sm2_w;
    else             srcb = sm3_w;
    float f = srcb[(size_t)co * 2304 + ci * 9 + tap];
    _Float16 h = (_Float16)f;
    _Float16 l = (_Float16)(f - (float)h);
    WH[idx] = h; WL[idx] = l;
}

// ---------------- MFMA conv3x3 (fp16 3-term split; f16-pair producer/consumer) --
// inPairs: stage hi/lo f16 pairs written by the PRODUCING mconv epilogue
// (two 4B loads/slot, zero cvt VALU) instead of fp32+convert. Pair planes
// live IN PLACE of the fp32 feature buffer: [128][HW] f16x2 hi, then lo
// (same byte footprint). Stored pair (h(v), v-h(v)) is bit-identical to what
// the old staging computed -> absmax unchanged.
// outPairs: epilogue writes pair planes (intermediates); else fp32 (det inputs).
struct MC {
    const float*    src[2][3];
    float*          dst[2][3];
    const _Float16* wh[2][3];
    const _Float16* wl[2][3];
    const float*    bias[2][3];
    int act;
    int nbr;
    int inPairs;
    int outPairs;
};

__launch_bounds__(256)
__global__ void mconv3x3(MC p)
{
    __shared__ __align__(16) _Float16 SH[2][108 * 40];
    __shared__ __align__(16) _Float16 SL[2][108 * 40];
    int t = threadIdx.x;
    int NS = 4 * p.nbr;
    int bid = blockIdx.x;
    int slice = bid % NS;
    int sp = bid / NS;                        // 0..139: 100 L3, 30 L4, 10 L5
    int br = slice % p.nbr;
    int co0 = (slice / p.nbr) * 64;
    int lvl = (sp < 100) ? 0 : (sp < 130) ? 1 : 2;
    int tloc = sp - ((lvl == 0) ? 0 : (lvl == 1) ? 100 : 130);
    int W = (lvl == 0) ? 80 : (lvl == 1) ? 40 : 20;
    int nTx = (lvl == 0) ? 5 : (lvl == 1) ? 3 : 2;
    int HW = W * W;
    int bx0 = (tloc % nTx) * 16, by0 = (tloc / nTx) * 4;
    const float* src = p.src[br][lvl];
    float* dst = p.dst[br][lvl];
    const _Float16* wh = p.wh[br][lvl];
    const _Float16* wl = p.wl[br][lvl];
    const float* bias = p.bias[br][lvl];
    const unsigned* PHsrc = (const unsigned*)src;            // hi pairs [128][HW]
    const unsigned* PLsrc = PHsrc + (size_t)128 * HW;        // lo pairs

    int lane = t & 63, wid = t >> 6;
    int cw = wid & 1, pw = wid >> 1;
    int colc = lane & 15, g = lane >> 4;

    // staging descriptors: 1728 ci-pair slots (108 cells x 16 pairs)
    int sgo[7], sci[7], sla[7];
#pragma unroll
    for (int k = 0; k < 7; ++k) {
        int s2 = t + k * 256;
        sgo[k] = -1; sci[k] = 0; sla[k] = 0;
        if (s2 < 1728) {
            int ci2 = s2 / 108, cell = s2 - ci2 * 108;
            int r = cell / 18, c = cell - r * 18;
            sla[k] = cell * 40 + ci2 * 2;
            sci[k] = ci2;
            int gy = by0 - 1 + r, gx = bx0 - 1 + c;
            if (gy >= 0 && gy < W && gx >= 0 && gx < W)
                sgo[k] = gy * W + gx;
        } else {
            sla[k] = -1;
        }
    }

    f32x4 acc[2][2];
#pragma unroll
    for (int mi = 0; mi < 2; ++mi)
#pragma unroll
        for (int ny = 0; ny < 2; ++ny) acc[mi][ny] = (f32x4)0.f;

    // stage chunk 0
#pragma unroll
    for (int k = 0; k < 7; ++k) {
        if (sla[k] >= 0) {
            unsigned hw_ = 0u, lw_ = 0u;
            if (sgo[k] >= 0) {
                if (p.inPairs) {
                    hw_ = PHsrc[(size_t)sci[k] * HW + sgo[k]];
                    lw_ = PLsrc[(size_t)sci[k] * HW + sgo[k]];
                } else {
                    float v0 = src[(size_t)(sci[k] * 2) * HW + sgo[k]];
                    float v1 = src[(size_t)(sci[k] * 2 + 1) * HW + sgo[k]];
                    _Float16 h0 = (_Float16)v0, h1 = (_Float16)v1;
                    _Float16 l0 = (_Float16)(v0 - (float)h0), l1 = (_Float16)(v1 - (float)h1);
                    f16x2 ph = {h0, h1}, pl = {l0, l1};
                    hw_ = *(unsigned*)&ph; lw_ = *(unsigned*)&pl;
                }
            }
            *(unsigned*)&SH[0][sla[k]] = hw_;
            *(unsigned*)&SL[0][sla[k]] = lw_;
        }
    }
    __syncthreads();

    int cob0 = (co0 + cw * 32) >> 4;          // mi=0 A-block; mi=1 is cob0+1
    auto aoff = [&](int ckk, int tap, int mi) -> size_t {
        return ((size_t)((tap * 16 + cob0 + mi) * 8 + ckk)) * 512 + lane * 8;
    };
    // 3-slot A-frag ring (indices compile-time after unroll)
    f16x8 Ah0[3], Al0[3], Ah1[3], Al1[3];
    {
        size_t a0 = aoff(0, 0, 0), a1 = aoff(0, 0, 1);
        Ah0[0] = *(const f16x8*)(wh + a0); Al0[0] = *(const f16x8*)(wl + a0);
        Ah1[0] = *(const f16x8*)(wh + a1); Al1[0] = *(const f16x8*)(wl + a1);
        a0 = aoff(0, 1, 0); a1 = aoff(0, 1, 1);
        Ah0[1] = *(const f16x8*)(wh + a0); Al0[1] = *(const f16x8*)(wl + a0);
        Ah1[1] = *(const f16x8*)(wh + a1); Al1[1] = *(const f16x8*)(wl + a1);
    }
    for (int ck = 0; ck < 8; ++ck) {
        const _Float16* sh  = SH[ck & 1];
        const _Float16* sl_ = SL[ck & 1];
        unsigned pv[14];
        bool pf = (ck < 7);
        if (pf) {
            if (p.inPairs) {
                const unsigned* ph = PHsrc + (size_t)(ck + 1) * 16 * HW;
                const unsigned* pl = PLsrc + (size_t)(ck + 1) * 16 * HW;
#pragma unroll
                for (int k = 0; k < 7; ++k) {
                    pv[2 * k] = 0u; pv[2 * k + 1] = 0u;
                    if (sla[k] >= 0 && sgo[k] >= 0) {
                        pv[2 * k]     = ph[(size_t)sci[k] * HW + sgo[k]];
                        pv[2 * k + 1] = pl[(size_t)sci[k] * HW + sgo[k]];
                    }
                }
            } else {
                const float* sb = src + (size_t)(ck + 1) * 32 * HW;
#pragma unroll
                for (int k = 0; k < 7; ++k) {
                    pv[2 * k] = 0u; pv[2 * k + 1] = 0u;
                    if (sla[k] >= 0 && sgo[k] >= 0) {
                        pv[2 * k]     = __float_as_uint(sb[(size_t)(sci[k] * 2) * HW + sgo[k]]);
                        pv[2 * k + 1] = __float_as_uint(sb[(size_t)(sci[k] * 2 + 1) * HW + sgo[k]]);
                    }
                }
            }
        }
#pragma unroll
        for (int tap = 0; tap < 9; ++tap) {
            int slot = tap % 3;
            int nsl  = (tap + 2) % 3;
            int pck = ck, ptap = tap + 2;
            if (ptap >= 9) { ptap -= 9; if (pf) pck = ck + 1; }
            size_t an0 = aoff(pck, ptap, 0), an1 = aoff(pck, ptap, 1);
            Ah0[nsl] = *(const f16x8*)(wh + an0);
            Al0[nsl] = *(const f16x8*)(wl + an0);
            Ah1[nsl] = *(const f16x8*)(wh + an1);
            Al1[nsl] = *(const f16x8*)(wl + an1);
            int ky = tap / 3, kx = tap - ky * 3;
#pragma unroll
            for (int ny = 0; ny < 2; ++ny) {
                int cell = (pw * 2 + ny + ky) * 18 + colc + kx;
                f16x8 bh = *(const f16x8*)(sh  + cell * 40 + g * 8);
                f16x8 bl = *(const f16x8*)(sl_ + cell * 40 + g * 8);
                acc[0][ny] = MFMA16(Ah0[slot], bh, acc[0][ny], 0, 0, 0);
                acc[1][ny] = MFMA16(Ah1[slot], bh, acc[1][ny], 0, 0, 0);
                acc[0][ny] = MFMA16(Ah0[slot], bl, acc[0][ny], 0, 0, 0);
                acc[1][ny] = MFMA16(Ah1[slot], bl, acc[1][ny], 0, 0, 0);
                acc[0][ny] = MFMA16(Al0[slot], bh, acc[0][ny], 0, 0, 0);
                acc[1][ny] = MFMA16(Al1[slot], bh, acc[1][ny], 0, 0, 0);
            }
        }
        if (pf) {
            _Float16* nh = SH[(ck + 1) & 1];
            _Float16* nl = SL[(ck + 1) & 1];
            if (p.inPairs) {
#pragma unroll
                for (int k = 0; k < 7; ++k) {
                    if (sla[k] >= 0) {
                        *(unsigned*)&nh[sla[k]] = pv[2 * k];
                        *(unsigned*)&nl[sla[k]] = pv[2 * k + 1];
                    }
                }
            } else {
#pragma unroll
                for (int k = 0; k < 7; ++k) {
                    if (sla[k] >= 0) {
                        float v0 = __uint_as_float(pv[2 * k]);
                        float v1 = __uint_as_float(pv[2 * k + 1]);
                        _Float16 h0 = (_Float16)v0, h1 = (_Float16)v1;
                        _Float16 l0 = (_Float16)(v0 - (float)h0), l1 = (_Float16)(v1 - (float)h1);
                        f16x2 ph = {h0, h1}, pl = {l0, l1};
                        *(unsigned*)&nh[sla[k]] = *(unsigned*)&ph;
                        *(unsigned*)&nl[sla[k]] = *(unsigned*)&pl;
                    }
                }
            }
        }
        __syncthreads();
    }

    int x = bx0 + colc;
    if (x < W) {
        unsigned* PHdst = (unsigned*)dst;
        unsigned* PLdst = PHdst + (size_t)128 * HW;
#pragma unroll
        for (int mi = 0; mi < 2; ++mi) {
            int cob = co0 + cw * 32 + mi * 16 + g * 4;
#pragma unroll
            for (int ny = 0; ny < 2; ++ny) {
                int y = by0 + pw * 2 + ny;
                int off = y * W + x;
                float v[4];
#pragma unroll
                for (int i = 0; i < 4; ++i) {
                    float vv = acc[mi][ny][i] + bias[cob + i];
                    if (p.act) vv = (vv >= 0.f) ? vv : 0.1f * vv;
                    v[i] = vv;
                }
                if (p.outPairs) {
#pragma unroll
                    for (int pr = 0; pr < 2; ++pr) {
                        float v0 = v[2 * pr], v1 = v[2 * pr + 1];
                        _Float16 h0 = (_Float16)v0, h1 = (_Float16)v1;
                        _Float16 l0 = (_Float16)(v0 - (float)h0), l1 = (_Float16)(v1 - (float)h1);
                        f16x2 ph = {h0, h1}, pl = {l0, l1};
                        size_t pidx = (size_t)(cob / 2 + pr) * HW + off;
                        PHdst[pidx] = *(unsigned*)&ph;
                        PLdst[pidx] = *(unsigned*)&pl;
                    }
                } else {
#pragma unroll
                    for (int i = 0; i < 4; ++i)
                        dst[(size_t)(cob + i) * HW + off] = v[i];
                }
            }
        }
    }
}

// ---------------- decode: scores, argmax, boxes, sort keys ----------------
__launch_bounds__(256)
__global__ void decode_kernel(const float* __restrict__ cls, const float* __restrict__ reg,
                              const float* __restrict__ ctn, float* __restrict__ out,
                              unsigned long long* __restrict__ keys)
{
    int p = blockIdx.x * 256 + threadIdx.x;
    if (p >= 16384) return;
    if (p >= 8400) { keys[p] = ~0ull; return; }
    int base, hs; float s;
    if (p < 6400)      { base = 0;    hs = 80; s = 8.f;  }
    else if (p < 8000) { base = 6400; hs = 40; s = 16.f; }
    else               { base = 8000; hs = 20; s = 32.f; }
    int local = p - base;
    float gx = (float)(local % hs), gy = (float)(local / hs);
    float ct = ctn[p];
    float sct = 1.f / (1.f + expf(-ct));
    float best = -1.f; int arg = 0;
    for (int c = 0; c < 80; ++c) {
        float v = cls[(size_t)c * 8400 + p];
        float sv = 1.f / (1.f + expf(-v));
        float sc = sqrtf(sv * sct);
        if (sc > best) { best = sc; arg = c; }
    }
    float r0 = reg[0 * 8400 + p], r1 = reg[1 * 8400 + p];
    float r2 = reg[2 * 8400 + p], r3 = reg[3 * 8400 + p];
    float x1 = (gx - expf(r0)) * s / 640.f;
    float y1 = (gy - expf(r1)) * s / 640.f;
    float x2 = (gx + expf(r2)) * s / 640.f;
    float y2 = (gy + expf(r3)) * s / 640.f;
    x1 = fminf(fmaxf(x1, 0.f), 1.f);
    y1 = fminf(fmaxf(y1, 0.f), 1.f);
    x2 = fminf(fmaxf(x2, 0.f), 1.f);
    y2 = fminf(fmaxf(y2, 0.f), 1.f);
    out[p * 4 + 0] = x1; out[p * 4 + 1] = y1;
    out[p * 4 + 2] = x2; out[p * 4 + 3] = y2;
    out[33600 + p] = best;
    out[42000 + p] = (float)arg;
    out[50400 + p] = 0.f;
    unsigned int ub = __float_as_uint(best);
    keys[p] = ((unsigned long long)(~ub) << 32) | (unsigned int)p;
}

// ---------------- hybrid bitonic sort of 16384 u64 keys ----------------
__launch_bounds__(256)
__global__ void bitonic_local(unsigned long long* __restrict__ keys, unsigned kmerge)
{
    __shared__ unsigned long long sk[2048];
    int t = threadIdx.x;
    unsigned base = blockIdx.x * 2048u;
#pragma unroll
    for (int m = 0; m < 8; ++m) sk[t + m * 256] = keys[base + t + m * 256];
    __syncthreads();
    if (kmerge == 0u) {
        for (unsigned k = 2; k <= 2048u; k <<= 1) {
            for (unsigned j = k >> 1; j > 0; j >>= 1) {
#pragma unroll
                for (int pp = 0; pp < 4; ++pp) {
                    unsigned p = (unsigned)t + pp * 256u;
                    unsigned li = ((p & ~(j - 1)) << 1) | (p & (j - 1));
                    unsigned gi = base + li;
                    bool up = ((gi & k) == 0);
                    unsigned long long a = sk[li], b = sk[li + j];
                    if ((a > b) == up) { sk[li] = b; sk[li + j] = a; }
                }
                __syncthreads();
            }
        }
    } else {
        unsigned k = kmerge;
        for (unsigned j = 1024; j > 0; j >>= 1) {
#pragma unroll
            for (int pp = 0; pp < 4; ++pp) {
                unsigned p = (unsigned)t + pp * 256u;
                unsigned li = ((p & ~(j - 1)) << 1) | (p & (j - 1));
                unsigned gi = base + li;
                bool up = ((gi & k) == 0);
                unsigned long long a = sk[li], b = sk[li + j];
                if ((a > b) == up) { sk[li] = b; sk[li + j] = a; }
            }
            __syncthreads();
        }
    }
#pragma unroll
    for (int m = 0; m < 8; ++m) keys[base + t + m * 256] = sk[t + m * 256];
}

__launch_bounds__(256)
__global__ void bitonic_global(unsigned long long* __restrict__ keys, unsigned k, unsigned j)
{
    unsigned p = blockIdx.x * 256u + threadIdx.x;
    unsigned i = ((p & ~(j - 1)) << 1) | (p & (j - 1));
    bool up = ((i & k) == 0);
    unsigned long long a = keys[i], b = keys[i + j];
    if ((a > b) == up) { keys[i] = b; keys[i + j] = a; }
}

// ---------------- expand sorted keys into SoA arrays ----------------
__launch_bounds__(256)
__global__ void sorted_aux(const unsigned long long* __restrict__ keys,
                           const float* __restrict__ out,
                           float* __restrict__ scs, int* __restrict__ clss,
                           int* __restrict__ idxs)
{
    int i = blockIdx.x * 256 + threadIdx.x;
    if (i >= 16384) return;
    unsigned long long key = keys[i];
    unsigned ub = ~(unsigned)(key >> 32);
    float sc = __uint_as_float(ub);
    unsigned idx = (unsigned)(key & 0xffffffffu);
    int cl = -1;
    if (idx < 8400u) cl = (int)out[42000 + idx];
    else sc = 0.f;
    scs[i] = sc; clss[i] = cl; idxs[i] = (int)idx;
}

// ---------------- NMS stage 1: per-class stable compaction (+ row->class map) ----
__launch_bounds__(256)
__global__ void compact_cls(const float* __restrict__ scs, const int* __restrict__ clss,
                            const int* __restrict__ idxs, const float* __restrict__ outbuf,
                            float* __restrict__ GX1, float* __restrict__ GY1,
                            float* __restrict__ GX2, float* __restrict__ GY2,
                            float* __restrict__ GAR, int* __restrict__ GIX,
                            int* __restrict__ CROW,
                            int* __restrict__ NCOUNT, int* __restrict__ NBASE)
{
    int c = blockIdx.x, t = threadIdx.x;
    __shared__ int s_red[2];
    __shared__ int s_wtot[4];
    int cb = 0, co = 0;
    for (int i = t; i < 16384; i += 256) {
        float sc = scs[i]; int cl = clss[i];
        if (sc >= CONF_T && cl >= 0) { cb += (cl < c); co += (cl == c); }
    }
    if (t == 0) { s_red[0] = 0; s_red[1] = 0; }
    __syncthreads();
    atomicAdd(&s_red[0], cb);
    atomicAdd(&s_red[1], co);
    __syncthreads();
    int base = s_red[0], n = s_red[1];
    if (t == 0) { NCOUNT[c] = n; NBASE[c] = base; }

    int rank = 0;
    for (int st = 0; st < 16384; st += 256) {
        int i = st + t;
        float sc = scs[i]; int cl = clss[i];
        bool flag = (sc >= CONF_T && cl == c);
        unsigned long long m = __ballot(flag);
        int lane = t & 63, wv = t >> 6;
        if (lane == 0) s_wtot[wv] = __popcll(m);
        __syncthreads();
        int off = rank;
        for (int w = 0; w < wv; ++w) off += s_wtot[w];
        int tot = s_wtot[0] + s_wtot[1] + s_wtot[2] + s_wtot[3];
        if (flag) {
            int pos = off + __popcll(m & ((1ull << lane) - 1ull));
            int idx = idxs[i];
            float x1 = outbuf[idx * 4 + 0], y1 = outbuf[idx * 4 + 1];
            float x2 = outbuf[idx * 4 + 2], y2 = outbuf[idx * 4 + 3];
            GX1[base + pos] = x1; GY1[base + pos] = y1;
            GX2[base + pos] = x2; GY2[base + pos] = y2;
            GAR[base + pos] = (x2 - x1) * (y2 - y1);
            GIX[base + pos] = idx;
            CROW[base + pos] = c;
        }
        rank += tot;
        __syncthreads();
    }
}

// ---------------- NMS stage 2: ballot mask + nonzero-word bitmap ----------------
__launch_bounds__(256)
__global__ void nms_mask(const float* __restrict__ GX1, const float* __restrict__ GY1,
                         const float* __restrict__ GX2, const float* __restrict__ GY2,
                         const float* __restrict__ GAR,
                         const int* __restrict__ CROW,
                         const int* __restrict__ NCOUNT, const int* __restrict__ NBASE,
                         unsigned long long* __restrict__ MASK,
                         unsigned long long* __restrict__ NZ)
{
    int lane = threadIdx.x & 63, wid = threadIdx.x >> 6;
    int gr = blockIdx.x * 4 + wid;
    int tot = NBASE[79] + NCOUNT[79];
    if (gr >= tot) return;
    int c = CROW[gr];
    int base = NBASE[c], n = NCOUNT[c];
    int r = gr - base;
    float rx1 = GX1[gr], ry1 = GY1[gr];
    float rx2 = GX2[gr], ry2 = GY2[gr];
    float rar = GAR[gr];
    int Wc = (n + 63) >> 6;
    unsigned long long nz0 = 0ull, nz1 = 0ull, nz2 = 0ull;
    for (int w = 0; w < Wc; ++w) {
        int jb = w * 64;
        unsigned long long m = 0ull;
        if (jb + 63 > r) {
            int j = jb + lane;
            bool pred = false;
            if (j > r && j < n) {
                float xx1 = fmaxf(rx1, GX1[base + j]);
                float yy1 = fmaxf(ry1, GY1[base + j]);
                float xx2 = fminf(rx2, GX2[base + j]);
                float yy2 = fminf(ry2, GY2[base + j]);
                float ww = fmaxf(1e-28f, xx2 - xx1);
                float hh = fmaxf(1e-28f, yy2 - yy1);
                float inter = ww * hh;
                float ovr = inter / (rar + GAR[base + j] - inter);
                pred = (ovr > NMS_T);
            }
            m = __ballot(pred);
        }
        if (lane == 0) {
            MASK[(size_t)gr * WMAX + w] = m;
            if (m) {
                if (w < 64)       nz0 |= 1ull << w;
                else if (w < 128) nz1 |= 1ull << (w - 64);
                else              nz2 |= 1ull << (w - 128);
            }
        }
    }
    if (lane == 0) {
        NZ[(size_t)gr * 4 + 0] = nz0;
        NZ[(size_t)gr * 4 + 1] = nz1;
        NZ[(size_t)gr * 4 + 2] = nz2;
    }
}

// ---------------- NMS stage 3: ffs scan + sparse-word OR (NZ bitmap) -----------
__launch_bounds__(256)
__global__ void nms_scan(const unsigned long long* __restrict__ MASK,
                         const unsigned long long* __restrict__ NZ,
                         const int* __restrict__ GIX,
                         const int* __restrict__ NCOUNT, const int* __restrict__ NBASE,
                         float* __restrict__ keep)
{
    int c = blockIdx.x, t = threadIdx.x;
    int n = NCOUNT[c];
    if (n == 0) return;
    int base = NBASE[c];
    int Wc = (n + 63) >> 6;
    __shared__ unsigned long long remv[WMAX];
    __shared__ unsigned long long sdiag[64];
    __shared__ unsigned long long s_am;
    __shared__ int s_rows[64];
    __shared__ int s_na;
    for (int w = t; w < Wc; w += 256) remv[w] = 0ull;
    __syncthreads();
    for (int i0 = 0; i0 < n; i0 += 64) {
        int rows = min(64, n - i0);
        int wq = i0 >> 6;
        if (t < rows) sdiag[t] = MASK[(size_t)(base + i0 + t) * WMAX + wq];
        __syncthreads();
        if (t == 0) {
            unsigned long long live = (rows < 64) ? ((1ull << rows) - 1ull) : ~0ull;
            live &= ~remv[wq];
            unsigned long long am = 0ull;
            int na = 0;
            while (live) {
                int rr = __ffsll((unsigned long long)live) - 1;
                am |= 1ull << rr;
                s_rows[na++] = rr;
                live &= ~sdiag[rr];
                live &= ~(1ull << rr);
            }
            s_am = am; s_na = na;
        }
        __syncthreads();
        unsigned long long am = s_am;
        int na = s_na;
        if (t < na) {
            int gr = base + i0 + s_rows[t];
#pragma unroll
            for (int part = 0; part < 3; ++part) {
                unsigned long long nz = NZ[(size_t)gr * 4 + part];
                while (nz) {
                    int b = __ffsll((unsigned long long)nz) - 1;
                    nz &= nz - 1ull;
                    int w = part * 64 + b;
                    atomicOr(&remv[w], MASK[(size_t)gr * WMAX + w]);
                }
            }
        }
        __syncthreads();
        if (t < rows && ((am >> t) & 1ull)) keep[GIX[base + i0 + t]] = 1.0f;
        __syncthreads();
    }
}

// ---------------- host orchestration ----------------
extern "C" void kernel_launch(void* const* d_in, const int* in_sizes, int n_in,
                              void* d_out, int out_size, void* d_ws, size_t ws_size,
                              hipStream_t stream)
{
    const float* c3      = (const float*)d_in[0];
    const float* c4      = (const float*)d_in[1];
    const float* c5      = (const float*)d_in[2];
    const float* lat1_w  = (const float*)d_in[3];
    const float* lat1_b  = (const float*)d_in[4];
    const float* lat2_w  = (const float*)d_in[5];
    const float* lat2_b  = (const float*)d_in[6];
    const float* lat3_w  = (const float*)d_in[7];
    const float* lat3_b  = (const float*)d_in[8];
    const float* sm1_w   = (const float*)d_in[9];
    const float* sm1_b   = (const float*)d_in[10];
    const float* sm2_w   = (const float*)d_in[11];
    const float* sm2_b   = (const float*)d_in[12];
    const float* sm3_w   = (const float*)d_in[13];
    const float* sm3_b   = (const float*)d_in[14];
    const float* clsh_w  = (const float*)d_in[15];
    const float* clsh_b  = (const float*)d_in[16];
    const float* regh_w  = (const float*)d_in[17];
    const float* regh_b  = (const float*)d_in[18];
    const float* clsd_w  = (const float*)d_in[19];
    const float* clsd_b  = (const float*)d_in[20];
    const float* regd_w  = (const float*)d_in[21];
    const float* regd_b  = (const float*)d_in[22];
    const float* ctnd_w  = (const float*)d_in[23];
    const float* ctnd_b  = (const float*)d_in[24];

    float* ws = (float*)d_ws;
    float* T3 = ws + OFF_T3;  float* T4 = ws + OFF_T4;  float* T5 = ws + OFF_T5;
    float* P3 = ws + OFF_P3;  float* P4 = ws + OFF_P4;  float* P5 = ws + OFF_P5;
    float* HA3 = ws + OFF_HA3; float* HA4 = ws + OFF_HA4; float* HA5 = ws + OFF_HA5;
    float* HB3 = ws + OFF_HB3; float* HB4 = ws + OFF_HB4; float* HB5 = ws + OFF_HB5;
    float* HD3 = ws + OFF_HD3; float* HD4 = ws + OFF_HD4; float* HD5 = ws + OFF_HD5;
    float* CLS = ws + OFF_CLS; float* REG = ws + OFF_REG; float* CTN = ws + OFF_CTN;
    _Float16* WH = (_Float16*)(ws + OFF_W2H);
    _Float16* WL = (_Float16*)(ws + OFF_W2L);
    unsigned long long* KEYS = (unsigned long long*)(ws + POFF_KEYS);
    float* SCS = ws + POFF_SCS;
    int* CLSS = (int*)(ws + POFF_CLSS);
    int* IDXS = (int*)(ws + POFF_IDXS);
    float* GX1 = ws + POFF_GX1; float* GY1 = ws + POFF_GY1;
    float* GX2 = ws + POFF_GX2; float* GY2 = ws + POFF_GY2;
    float* GAR = ws + POFF_GAR;
    int* GIX = (int*)(ws + POFF_GIX);
    int* CROW = (int*)(ws + POFF_CROW);
    int* NCOUNT = (int*)(ws + POFF_NCNT);
    int* NBASE  = (int*)(ws + POFF_NBASE);
    unsigned long long* NZ = (unsigned long long*)(ws + POFF_NZ);
    unsigned long long* MASK = (unsigned long long*)(ws + POFF_MASK);

    float* out = (float*)d_out;
    dim3 blk(256);

    // weight f16 hi/lo prep (11 matrices, fragment-order layout)
    w2prep<<<dim3((11 * WSTEP9 + 255) / 256), blk, 0, stream>>>(
        clsh_w, regh_w, sm1_w, sm2_w, sm3_w, WH, WL);

    // FPN laterals (dependency chain), then all smooths fused (MFMA)
    conv1x1_kernel<<<dim3(7, 4), blk, 0, stream>>>(c5, lat3_w, lat3_b, T5, nullptr,
                                                   512, 256, 400, 20, 400, 0);
    conv1x1_kernel<<<dim3(25, 4), blk, 0, stream>>>(c4, lat2_w, lat2_b, T4, T5,
                                                    256, 256, 1600, 40, 1600, 0);
    conv1x1_kernel<<<dim3(100, 4), blk, 0, stream>>>(c3, lat1_w, lat1_b, T3, T4,
                                                     128, 256, 6400, 80, 6400, 0);
    {
        MC mc{};
        float* sT[3] = {T3, T4, T5};
        float* sP[3] = {P3, P4, P5};
        const float* sB[3] = {sm1_b, sm2_b, sm3_b};
        for (int l = 0; l < 3; ++l) {
            mc.src[0][l] = sT[l]; mc.dst[0][l] = sP[l];
            mc.wh[0][l] = WH + (size_t)(8 + l) * WSTEP9;
            mc.wl[0][l] = WL + (size_t)(8 + l) * WSTEP9;
            mc.bias[0][l] = sB[l];
        }
        mc.act = 0; mc.nbr = 1; mc.inPairs = 0; mc.outPairs = 1;
        mconv3x3<<<dim3(140 * 4), blk, 0, stream>>>(mc);
    }
    // heads: 4 MFMA layers (pairs in; pairs out except last layer -> fp32)
    {
        float* clsS[3][5] = { {P3, HA3, HB3, HA3, HB3},
                              {P4, HA4, HB4, HA4, HB4},
                              {P5, HA5, HB5, HA5, HB5} };
        float* regS[3][5] = { {P3, T3,  HD3, T3,  HD3},
                              {P4, T4,  HD4, T4,  HD4},
                              {P5, T5,  HD5, T5,  HD5} };
        for (int i = 0; i < 4; ++i) {
            MC mc{};
            for (int l = 0; l < 3; ++l) {
                mc.src[0][l] = clsS[l][i]; mc.dst[0][l] = clsS[l][i + 1];
                mc.src[1][l] = regS[l][i]; mc.dst[1][l] = regS[l][i + 1];
                mc.wh[0][l] = WH + (size_t)i * WSTEP9;
                mc.wl[0][l] = WL + (size_t)i * WSTEP9;
                mc.wh[1][l] = WH + (size_t)(4 + i) * WSTEP9;
                mc.wl[1][l] = WL + (size_t)(4 + i) * WSTEP9;
                mc.bias[0][l] = clsh_b + i * 256;
                mc.bias[1][l] = regh_b + i * 256;
            }
            mc.act = 1; mc.nbr = 2;
            mc.inPairs = 1;
            mc.outPairs = (i < 3) ? 1 : 0;
            mconv3x3<<<dim3(140 * 8), blk, 0, stream>>>(mc);
        }
    }

    // ---- detectors: all 9 (level x {cls,reg,ctn}) in one dispatch ----
    {
        Det9 d;
        const float* feats[3][2] = { {HB3, HD3}, {HB4, HD4}, {HB5, HD5} };
        int   npx[3]   = {6400, 1600, 400};
        int   obase[3] = {0, 6400, 8000};
        int q = 0, bacc = 0;
        for (int l = 0; l < 3; ++l) {
            d.src[q] = feats[l][0]; d.w[q] = clsd_w; d.b[q] = clsd_b; d.dst[q] = CLS;
            d.cout[q] = 80; d.npx[q] = npx[l]; d.obase[q] = obase[l];
            d.bstart[q] = bacc; d.npxb[q] = (npx[l] + 63) / 64;
            bacc += d.npxb[q] * 2; ++q;
            d.src[q] = feats[l][1]; d.w[q] = regd_w; d.b[q] = regd_b; d.dst[q] = REG;
            d.cout[q] = 4; d.npx[q] = npx[l]; d.obase[q] = obase[l];
            d.bstart[q] = bacc; d.npxb[q] = (npx[l] + 63) / 64;
            bacc += d.npxb[q]; ++q;
            d.src[q] = feats[l][1]; d.w[q] = ctnd_w; d.b[q] = ctnd_b; d.dst[q] = CTN;
            d.cout[q] = 1; d.npx[q] = npx[l]; d.obase[q] = obase[l];
            d.bstart[q] = bacc; d.npxb[q] = (npx[l] + 63) / 64;
            bacc += d.npxb[q]; ++q;
        }
        det1x1_fused<<<dim3(bacc), blk, 0, stream>>>(d);
    }

    // ---- decode ----
    decode_kernel<<<dim3(64), blk, 0, stream>>>(CLS, REG, CTN, out, KEYS);

    // ---- hybrid bitonic sort ----
    bitonic_local<<<dim3(8), blk, 0, stream>>>(KEYS, 0u);
    bitonic_global<<<dim3(32), blk, 0, stream>>>(KEYS, 4096u, 2048u);
    bitonic_local<<<dim3(8), blk, 0, stream>>>(KEYS, 4096u);
    bitonic_global<<<dim3(32), blk, 0, stream>>>(KEYS, 8192u, 4096u);
    bitonic_global<<<dim3(32), blk, 0, stream>>>(KEYS, 8192u, 2048u);
    bitonic_local<<<dim3(8), blk, 0, stream>>>(KEYS, 8192u);
    bitonic_global<<<dim3(32), blk, 0, stream>>>(KEYS, 16384u, 8192u);
    bitonic_global<<<dim3(32), blk, 0, stream>>>(KEYS, 16384u, 4096u);
    bitonic_global<<<dim3(32), blk, 0, stream>>>(KEYS, 16384u, 2048u);
    bitonic_local<<<dim3(8), blk, 0, stream>>>(KEYS, 16384u);

    // ---- NMS pipeline ----
    sorted_aux<<<dim3(64), blk, 0, stream>>>(KEYS, out, SCS, CLSS, IDXS);
    compact_cls<<<dim3(80), blk, 0, stream>>>(SCS, CLSS, IDXS, out,
                                              GX1, GY1, GX2, GY2, GAR, GIX, CROW,
                                              NCOUNT, NBASE);
    nms_mask<<<dim3(2100), blk, 0, stream>>>(GX1, GY1, GX2, GY2, GAR, CROW,
                                             NCOUNT, NBASE, MASK, NZ);
    nms_scan<<<dim3(80), blk, 0, stream>>>(MASK, NZ, GIX, NCOUNT, NBASE, out + 50400);
}

// Round 23
// 936.704 us; speedup vs baseline: 1.0603x; 1.0603x over previous
//
#include <hip/hip_runtime.h>
#include <stdint.h>

#define CONF_T 0.05f
#define NMS_T  0.5f
#define WMAX   132           // ceil(8400/64)
#define WSTEP9 589824        // 256*256*9

typedef _Float16 f16x8 __attribute__((ext_vector_type(8)));
typedef _Float16 f16x2 __attribute__((ext_vector_type(2)));
typedef float    f32x4 __attribute__((ext_vector_type(4)));
#define MFMA16 __builtin_amdgcn_mfma_f32_16x16x32_f16

// ---- workspace layout (float offsets) ----
#define OFF_T3   0u
#define OFF_T4   1638400u
#define OFF_T5   2048000u
#define OFF_P3   2150400u
#define OFF_P4   3788800u
#define OFF_P5   4198400u
#define OFF_HA3  4300800u
#define OFF_HA4  5939200u
#define OFF_HA5  6348800u
#define OFF_HB3  6451200u
#define OFF_HB4  8089600u
#define OFF_HB5  8499200u
#define OFF_HD3  8601600u
#define OFF_HD4  10240000u
#define OFF_HD5  10649600u
#define OFF_CLS  10752000u
#define OFF_REG  11424000u
#define OFF_CTN  11457600u
#define OFF_W2H  11466000u                 // 11 matrices x 589824 f16 (hi)
#define OFF_W2L  14710032u                 // (lo)
#define WS_NEED  17954064u
// post-processing arrays (T3 region, free after conv stack)
#define POFF_KEYS  (OFF_T3 + 0u)
#define POFF_SCS   (OFF_T3 + 32768u)
#define POFF_CLSS  (OFF_T3 + 49152u)
#define POFF_IDXS  (OFF_T3 + 65536u)
#define POFF_GX1   (OFF_T3 + 81920u)
#define POFF_GY1   (OFF_T3 + 90320u)
#define POFF_GX2   (OFF_T3 + 98720u)
#define POFF_GY2   (OFF_T3 + 107120u)
#define POFF_GAR   (OFF_T3 + 115520u)
#define POFF_GIX   (OFF_T3 + 123920u)
#define POFF_NCNT  (OFF_T3 + 132320u)
#define POFF_NBASE (OFF_T3 + 132400u)
#define POFF_CROW  (OFF_T3 + 132480u)      // 8400 ints: compacted row -> class
#define POFF_NZ    (OFF_T3 + 140880u)      // 8400 x 4 u64 nonzero-word bitmaps
#define POFF_MASK  OFF_HA3

// ---------------- conv 1x1 (+ optional nearest-up2 add) ----------------
__launch_bounds__(256)
__global__ void conv1x1_kernel(const float* __restrict__ in, const float* __restrict__ w,
                               const float* __restrict__ b, float* __restrict__ out,
                               const float* __restrict__ add,
                               int Cin, int Cout, int NPX, int W, int outStride, int outBase)
{
    __shared__ float s_in[16][64];
    __shared__ float s_w[16][64];
    int t = threadIdx.x;
    int pxg = t & 31, cg = t >> 5;
    int px0 = blockIdx.x * 64;
    int co0 = blockIdx.y * 64;
    float acc[8][2];
#pragma unroll
    for (int c = 0; c < 8; ++c) { acc[c][0] = 0.f; acc[c][1] = 0.f; }
    int chunks = Cin >> 4;
    int wco = t >> 2, wpart = t & 3;
    for (int ch = 0; ch < chunks; ++ch) {
        int ci0 = ch << 4;
#pragma unroll
        for (int k = 0; k < 4; ++k) {
            int id = t + k * 256;
            int ci = id >> 6, pp = id & 63;
            int gp = px0 + pp;
            s_in[ci][pp] = (gp < NPX) ? in[(size_t)(ci0 + ci) * NPX + gp] : 0.f;
        }
        {
            int gco = co0 + wco;
            if (gco < Cout) {
                const float* run = w + (size_t)gco * Cin + ci0;
#pragma unroll
                for (int k = 0; k < 4; ++k) {
                    int e = wpart + 4 * k;
                    s_w[e][wco] = run[e];
                }
            } else {
#pragma unroll
                for (int k = 0; k < 4; ++k) s_w[wpart + 4 * k][wco] = 0.f;
            }
        }
        __syncthreads();
#pragma unroll
        for (int ci = 0; ci < 16; ++ci) {
            float i0 = s_in[ci][pxg * 2], i1 = s_in[ci][pxg * 2 + 1];
#pragma unroll
            for (int c = 0; c < 8; ++c) {
                float wv = s_w[ci][cg * 8 + c];
                acc[c][0] += wv * i0;
                acc[c][1] += wv * i1;
            }
        }
        __syncthreads();
    }
    for (int c = 0; c < 8; ++c) {
        int co = co0 + cg * 8 + c;
        if (co >= Cout) break;
        float bb = b[co];
#pragma unroll
        for (int j = 0; j < 2; ++j) {
            int p = px0 + pxg * 2 + j;
            if (p < NPX) {
                float v = acc[c][j] + bb;
                if (add) {
                    int y = p / W, x = p % W;
                    int Sp = W >> 1;
                    v += add[(size_t)co * (Sp * Sp) + (y >> 1) * Sp + (x >> 1)];
                }
                out[(size_t)co * outStride + outBase + p] = v;
            }
        }
    }
}

// ---------------- fused detector 1x1 (9 combos in one dispatch) ----------------
struct Det9 {
    const float* src[9]; const float* w[9]; const float* b[9];
    float*       dst[9];
    int cout[9], npx[9], obase[9], bstart[9], npxb[9];
};

__launch_bounds__(256)
__global__ void det1x1_fused(Det9 d)
{
    int bid = blockIdx.x;
    int q = 0;
#pragma unroll
    for (int i = 1; i < 9; ++i) if (bid >= d.bstart[i]) q = i;
    int local = bid - d.bstart[q];
    int coIdx = local / d.npxb[q];
    int pxIdx = local - coIdx * d.npxb[q];
    const float* in = d.src[q];
    const float* w  = d.w[q];
    const float* b  = d.b[q];
    float* out = d.dst[q];
    int Cout = d.cout[q], NPX = d.npx[q], outBase = d.obase[q];

    __shared__ float s_in[16][64];
    __shared__ float s_w[16][64];
    int t = threadIdx.x;
    int pxg = t & 31, cg = t >> 5;
    int px0 = pxIdx * 64;
    int co0 = coIdx * 64;
    float acc[8][2];
#pragma unroll
    for (int c = 0; c < 8; ++c) { acc[c][0] = 0.f; acc[c][1] = 0.f; }
    int wco = t >> 2, wpart = t & 3;
    for (int ch = 0; ch < 16; ++ch) {
        int ci0 = ch << 4;
#pragma unroll
        for (int k = 0; k < 4; ++k) {
            int id = t + k * 256;
            int ci = id >> 6, pp = id & 63;
            int gp = px0 + pp;
            s_in[ci][pp] = (gp < NPX) ? in[(size_t)(ci0 + ci) * NPX + gp] : 0.f;
        }
        {
            int gco = co0 + wco;
            if (gco < Cout) {
                const float* run = w + (size_t)gco * 256 + ci0;
#pragma unroll
                for (int k = 0; k < 4; ++k) {
                    int e = wpart + 4 * k;
                    s_w[e][wco] = run[e];
                }
            } else {
#pragma unroll
                for (int k = 0; k < 4; ++k) s_w[wpart + 4 * k][wco] = 0.f;
            }
        }
        __syncthreads();
#pragma unroll
        for (int ci = 0; ci < 16; ++ci) {
            float i0 = s_in[ci][pxg * 2], i1 = s_in[ci][pxg * 2 + 1];
#pragma unroll
            for (int c = 0; c < 8; ++c) {
                float wv = s_w[ci][cg * 8 + c];
                acc[c][0] += wv * i0;
                acc[c][1] += wv * i1;
            }
        }
        __syncthreads();
    }
    for (int c = 0; c < 8; ++c) {
        int co = co0 + cg * 8 + c;
        if (co >= Cout) break;
        float bb = b[co];
#pragma unroll
        for (int j = 0; j < 2; ++j) {
            int p = px0 + pxg * 2 + j;
            if (p < NPX) out[(size_t)co * 8400 + outBase + p] = acc[c][j] + bb;
        }
    }
}

// ---------------- MFMA path: weight f16 hi/lo prep (FRAGMENT-ORDER layout) ----
__launch_bounds__(256)
__global__ void w2prep(const float* __restrict__ clsh_w, const float* __restrict__ regh_w,
                       const float* __restrict__ sm1_w, const float* __restrict__ sm2_w,
                       const float* __restrict__ sm3_w,
                       _Float16* __restrict__ WH, _Float16* __restrict__ WL)
{
    int idx = blockIdx.x * 256 + threadIdx.x;
    if (idx >= 11 * WSTEP9) return;
    int m = idx / WSTEP9, e = idx - m * WSTEP9;
    int tap = e / 65536;            // 16 cob * 8 ck * 512
    int r   = e - tap * 65536;
    int cob = r / 4096;             // 8 ck * 512
    int r2  = r - cob * 4096;
    int ck  = r2 / 512;
    int r3  = r2 - ck * 512;
    int lane = r3 / 8, el = r3 - (r3 / 8) * 8;
    int co = cob * 16 + (lane & 15);
    int ci = ck * 32 + (lane >> 4) * 8 + el;
    const float* srcb;
    if (m < 4)       srcb = clsh_w + (size_t)m * WSTEP9;
    else if (m < 8)  srcb = regh_w + (size_t)(m - 4) * WSTEP9;
    else if (m == 8) srcb = sm1_w;
    else if (m == 9) srcb = sm2_w;
    else             srcb = sm3_w;
    float f = srcb[(size_t)co * 2304 + ci * 9 + tap];
    _Float16 h = (_Float16)f;
    _Float16 l = (_Float16)(f - (float)h);
    WH[idx] = h; WL[idx] = l;
}

// ---------------- MFMA conv3x3 (fp16 3-term split) ----------------
struct MC {
    const float*    src[2][3];
    float*          dst[2][3];
    const _Float16* wh[2][3];
    const _Float16* wl[2][3];
    const float*    bias[2][3];
    int act;
    int nbr;
};

__launch_bounds__(256)
__global__ void mconv3x3(MC p)
{
    __shared__ __align__(16) _Float16 SH[2][108 * 40];
    __shared__ __align__(16) _Float16 SL[2][108 * 40];
    int t = threadIdx.x;
    int NS = 4 * p.nbr;
    int bid = blockIdx.x;
    int slice = bid % NS;
    int sp = bid / NS;                        // 0..139: 100 L3, 30 L4, 10 L5
    int br = slice % p.nbr;
    int co0 = (slice / p.nbr) * 64;
    int lvl = (sp < 100) ? 0 : (sp < 130) ? 1 : 2;
    int tloc = sp - ((lvl == 0) ? 0 : (lvl == 1) ? 100 : 130);
    int W = (lvl == 0) ? 80 : (lvl == 1) ? 40 : 20;
    int nTx = (lvl == 0) ? 5 : (lvl == 1) ? 3 : 2;
    int HW = W * W;
    int bx0 = (tloc % nTx) * 16, by0 = (tloc / nTx) * 4;
    const float* src = p.src[br][lvl];
    float* dst = p.dst[br][lvl];
    const _Float16* wh = p.wh[br][lvl];
    const _Float16* wl = p.wl[br][lvl];
    const float* bias = p.bias[br][lvl];

    int lane = t & 63, wid = t >> 6;
    int cw = wid & 1, pw = wid >> 1;
    int colc = lane & 15, g = lane >> 4;

    // staging descriptors: 1728 ci-pair slots (108 cells x 16 pairs)
    int sgo[7], sla[7];
#pragma unroll
    for (int k = 0; k < 7; ++k) {
        int s2 = t + k * 256;
        sgo[k] = -1; sla[k] = 0;
        if (s2 < 1728) {
            int ci2 = s2 / 108, cell = s2 - ci2 * 108;
            int r = cell / 18, c = cell - r * 18;
            sla[k] = cell * 40 + ci2 * 2;
            int gy = by0 - 1 + r, gx = bx0 - 1 + c;
            if (gy >= 0 && gy < W && gx >= 0 && gx < W)
                sgo[k] = (ci2 * 2) * HW + gy * W + gx;
        }
    }

    f32x4 acc[2][2];
#pragma unroll
    for (int mi = 0; mi < 2; ++mi)
#pragma unroll
        for (int ny = 0; ny < 2; ++ny) acc[mi][ny] = (f32x4)0.f;

    // stage chunk 0
#pragma unroll
    for (int k = 0; k < 7; ++k) {
        if (t + k * 256 < 1728) {
            float v0 = 0.f, v1 = 0.f;
            if (sgo[k] >= 0) { v0 = src[sgo[k]]; v1 = src[sgo[k] + HW]; }
            _Float16 h0 = (_Float16)v0, h1 = (_Float16)v1;
            _Float16 l0 = (_Float16)(v0 - (float)h0), l1 = (_Float16)(v1 - (float)h1);
            f16x2 ph = {h0, h1}, pl = {l0, l1};
            *(f16x2*)&SH[0][sla[k]] = ph;
            *(f16x2*)&SL[0][sla[k]] = pl;
        }
    }
    __syncthreads();

    int cob0 = (co0 + cw * 32) >> 4;          // mi=0 A-block; mi=1 is cob0+1
    auto aoff = [&](int ckk, int tap, int mi) -> size_t {
        return ((size_t)((tap * 16 + cob0 + mi) * 8 + ckk)) * 512 + lane * 8;
    };
    // 3-slot A-frag ring (indices compile-time after unroll)
    f16x8 Ah0[3], Al0[3], Ah1[3], Al1[3];
    {
        size_t a0 = aoff(0, 0, 0), a1 = aoff(0, 0, 1);
        Ah0[0] = *(const f16x8*)(wh + a0); Al0[0] = *(const f16x8*)(wl + a0);
        Ah1[0] = *(const f16x8*)(wh + a1); Al1[0] = *(const f16x8*)(wl + a1);
        a0 = aoff(0, 1, 0); a1 = aoff(0, 1, 1);
        Ah0[1] = *(const f16x8*)(wh + a0); Al0[1] = *(const f16x8*)(wl + a0);
        Ah1[1] = *(const f16x8*)(wh + a1); Al1[1] = *(const f16x8*)(wl + a1);
    }
    for (int ck = 0; ck < 8; ++ck) {
        const _Float16* sh  = SH[ck & 1];
        const _Float16* sl_ = SL[ck & 1];
        float pv[14];
        bool pf = (ck < 7);
        if (pf) {
            const float* sb = src + (size_t)(ck + 1) * 32 * HW;
#pragma unroll
            for (int k = 0; k < 7; ++k) {
                pv[2 * k] = 0.f; pv[2 * k + 1] = 0.f;
                if (t + k * 256 < 1728 && sgo[k] >= 0) {
                    pv[2 * k] = sb[sgo[k]]; pv[2 * k + 1] = sb[sgo[k] + HW];
                }
            }
        }
#pragma unroll
        for (int tap = 0; tap < 9; ++tap) {
            int ky = tap / 3, kx = tap - ky * 3;
            int slot = tap % 3;
            int nsl  = (tap + 2) % 3;
            int pck = ck, ptap = tap + 2;
            if (ptap >= 9) { ptap -= 9; if (pf) pck = ck + 1; }
            size_t an0 = aoff(pck, ptap, 0), an1 = aoff(pck, ptap, 1);
            Ah0[nsl] = *(const f16x8*)(wh + an0);
            Al0[nsl] = *(const f16x8*)(wl + an0);
            Ah1[nsl] = *(const f16x8*)(wh + an1);
            Al1[nsl] = *(const f16x8*)(wl + an1);
#pragma unroll
            for (int ny = 0; ny < 2; ++ny) {
                int cell = (pw * 2 + ny + ky) * 18 + colc + kx;
                f16x8 bh = *(const f16x8*)(sh  + cell * 40 + g * 8);
                f16x8 bl = *(const f16x8*)(sl_ + cell * 40 + g * 8);
                acc[0][ny] = MFMA16(Ah0[slot], bh, acc[0][ny], 0, 0, 0);
                acc[1][ny] = MFMA16(Ah1[slot], bh, acc[1][ny], 0, 0, 0);
                acc[0][ny] = MFMA16(Ah0[slot], bl, acc[0][ny], 0, 0, 0);
                acc[1][ny] = MFMA16(Ah1[slot], bl, acc[1][ny], 0, 0, 0);
                acc[0][ny] = MFMA16(Al0[slot], bh, acc[0][ny], 0, 0, 0);
                acc[1][ny] = MFMA16(Al1[slot], bh, acc[1][ny], 0, 0, 0);
            }
        }
        if (pf) {
            _Float16* nh = SH[(ck + 1) & 1];
            _Float16* nl = SL[(ck + 1) & 1];
#pragma unroll
            for (int k = 0; k < 7; ++k) {
                if (t + k * 256 < 1728) {
                    float v0 = pv[2 * k], v1 = pv[2 * k + 1];
                    _Float16 h0 = (_Float16)v0, h1 = (_Float16)v1;
                    _Float16 l0 = (_Float16)(v0 - (float)h0), l1 = (_Float16)(v1 - (float)h1);
                    f16x2 ph = {h0, h1}, pl = {l0, l1};
                    *(f16x2*)&nh[sla[k]] = ph;
                    *(f16x2*)&nl[sla[k]] = pl;
                }
            }
        }
        __syncthreads();
    }

    int x = bx0 + colc;
    if (x < W) {
#pragma unroll
        for (int mi = 0; mi < 2; ++mi) {
            int cob = co0 + cw * 32 + mi * 16 + g * 4;
#pragma unroll
            for (int ny = 0; ny < 2; ++ny) {
                int y = by0 + pw * 2 + ny;
#pragma unroll
                for (int i = 0; i < 4; ++i) {
                    int co = cob + i;
                    float v = acc[mi][ny][i] + bias[co];
                    if (p.act) v = (v >= 0.f) ? v : 0.1f * v;
                    dst[(size_t)co * HW + y * W + x] = v;
                }
            }
        }
    }
}

// ---------------- decode: scores, argmax, boxes, sort keys ----------------
__launch_bounds__(256)
__global__ void decode_kernel(const float* __restrict__ cls, const float* __restrict__ reg,
                              const float* __restrict__ ctn, float* __restrict__ out,
                              unsigned long long* __restrict__ keys)
{
    int p = blockIdx.x * 256 + threadIdx.x;
    if (p >= 16384) return;
    if (p >= 8400) { keys[p] = ~0ull; return; }
    int base, hs; float s;
    if (p < 6400)      { base = 0;    hs = 80; s = 8.f;  }
    else if (p < 8000) { base = 6400; hs = 40; s = 16.f; }
    else               { base = 8000; hs = 20; s = 32.f; }
    int local = p - base;
    float gx = (float)(local % hs), gy = (float)(local / hs);
    float ct = ctn[p];
    float sct = 1.f / (1.f + expf(-ct));
    float best = -1.f; int arg = 0;
    for (int c = 0; c < 80; ++c) {
        float v = cls[(size_t)c * 8400 + p];
        float sv = 1.f / (1.f + expf(-v));
        float sc = sqrtf(sv * sct);
        if (sc > best) { best = sc; arg = c; }
    }
    float r0 = reg[0 * 8400 + p], r1 = reg[1 * 8400 + p];
    float r2 = reg[2 * 8400 + p], r3 = reg[3 * 8400 + p];
    float x1 = (gx - expf(r0)) * s / 640.f;
    float y1 = (gy - expf(r1)) * s / 640.f;
    float x2 = (gx + expf(r2)) * s / 640.f;
    float y2 = (gy + expf(r3)) * s / 640.f;
    x1 = fminf(fmaxf(x1, 0.f), 1.f);
    y1 = fminf(fmaxf(y1, 0.f), 1.f);
    x2 = fminf(fmaxf(x2, 0.f), 1.f);
    y2 = fminf(fmaxf(y2, 0.f), 1.f);
    out[p * 4 + 0] = x1; out[p * 4 + 1] = y1;
    out[p * 4 + 2] = x2; out[p * 4 + 3] = y2;
    out[33600 + p] = best;
    out[42000 + p] = (float)arg;
    out[50400 + p] = 0.f;
    unsigned int ub = __float_as_uint(best);
    keys[p] = ((unsigned long long)(~ub) << 32) | (unsigned int)p;
}

// ---------------- hybrid bitonic sort of 16384 u64 keys ----------------
__launch_bounds__(256)
__global__ void bitonic_local(unsigned long long* __restrict__ keys, unsigned kmerge)
{
    __shared__ unsigned long long sk[2048];
    int t = threadIdx.x;
    unsigned base = blockIdx.x * 2048u;
#pragma unroll
    for (int m = 0; m < 8; ++m) sk[t + m * 256] = keys[base + t + m * 256];
    __syncthreads();
    if (kmerge == 0u) {
        for (unsigned k = 2; k <= 2048u; k <<= 1) {
            for (unsigned j = k >> 1; j > 0; j >>= 1) {
#pragma unroll
                for (int pp = 0; pp < 4; ++pp) {
                    unsigned p = (unsigned)t + pp * 256u;
                    unsigned li = ((p & ~(j - 1)) << 1) | (p & (j - 1));
                    unsigned gi = base + li;
                    bool up = ((gi & k) == 0);
                    unsigned long long a = sk[li], b = sk[li + j];
                    if ((a > b) == up) { sk[li] = b; sk[li + j] = a; }
                }
                __syncthreads();
            }
        }
    } else {
        unsigned k = kmerge;
        for (unsigned j = 1024; j > 0; j >>= 1) {
#pragma unroll
            for (int pp = 0; pp < 4; ++pp) {
                unsigned p = (unsigned)t + pp * 256u;
                unsigned li = ((p & ~(j - 1)) << 1) | (p & (j - 1));
                unsigned gi = base + li;
                bool up = ((gi & k) == 0);
                unsigned long long a = sk[li], b = sk[li + j];
                if ((a > b) == up) { sk[li] = b; sk[li + j] = a; }
            }
            __syncthreads();
        }
    }
#pragma unroll
    for (int m = 0; m < 8; ++m) keys[base + t + m * 256] = sk[t + m * 256];
}

__launch_bounds__(256)
__global__ void bitonic_global(unsigned long long* __restrict__ keys, unsigned k, unsigned j)
{
    unsigned p = blockIdx.x * 256u + threadIdx.x;
    unsigned i = ((p & ~(j - 1)) << 1) | (p & (j - 1));
    bool up = ((i & k) == 0);
    unsigned long long a = keys[i], b = keys[i + j];
    if ((a > b) == up) { keys[i] = b; keys[i + j] = a; }
}

// ---------------- expand sorted keys into SoA arrays ----------------
__launch_bounds__(256)
__global__ void sorted_aux(const unsigned long long* __restrict__ keys,
                           const float* __restrict__ out,
                           float* __restrict__ scs, int* __restrict__ clss,
                           int* __restrict__ idxs)
{
    int i = blockIdx.x * 256 + threadIdx.x;
    if (i >= 16384) return;
    unsigned long long key = keys[i];
    unsigned ub = ~(unsigned)(key >> 32);
    float sc = __uint_as_float(ub);
    unsigned idx = (unsigned)(key & 0xffffffffu);
    int cl = -1;
    if (idx < 8400u) cl = (int)out[42000 + idx];
    else sc = 0.f;
    scs[i] = sc; clss[i] = cl; idxs[i] = (int)idx;
}

// ---------------- NMS stage 1: per-class stable compaction (+ row->class map) ----
__launch_bounds__(256)
__global__ void compact_cls(const float* __restrict__ scs, const int* __restrict__ clss,
                            const int* __restrict__ idxs, const float* __restrict__ outbuf,
                            float* __restrict__ GX1, float* __restrict__ GY1,
                            float* __restrict__ GX2, float* __restrict__ GY2,
                            float* __restrict__ GAR, int* __restrict__ GIX,
                            int* __restrict__ CROW,
                            int* __restrict__ NCOUNT, int* __restrict__ NBASE)
{
    int c = blockIdx.x, t = threadIdx.x;
    __shared__ int s_red[2];
    __shared__ int s_wtot[4];
    int cb = 0, co = 0;
    for (int i = t; i < 16384; i += 256) {
        float sc = scs[i]; int cl = clss[i];
        if (sc >= CONF_T && cl >= 0) { cb += (cl < c); co += (cl == c); }
    }
    if (t == 0) { s_red[0] = 0; s_red[1] = 0; }
    __syncthreads();
    atomicAdd(&s_red[0], cb);
    atomicAdd(&s_red[1], co);
    __syncthreads();
    int base = s_red[0], n = s_red[1];
    if (t == 0) { NCOUNT[c] = n; NBASE[c] = base; }

    int rank = 0;
    for (int st = 0; st < 16384; st += 256) {
        int i = st + t;
        float sc = scs[i]; int cl = clss[i];
        bool flag = (sc >= CONF_T && cl == c);
        unsigned long long m = __ballot(flag);
        int lane = t & 63, wv = t >> 6;
        if (lane == 0) s_wtot[wv] = __popcll(m);
        __syncthreads();
        int off = rank;
        for (int w = 0; w < wv; ++w) off += s_wtot[w];
        int tot = s_wtot[0] + s_wtot[1] + s_wtot[2] + s_wtot[3];
        if (flag) {
            int pos = off + __popcll(m & ((1ull << lane) - 1ull));
            int idx = idxs[i];
            float x1 = outbuf[idx * 4 + 0], y1 = outbuf[idx * 4 + 1];
            float x2 = outbuf[idx * 4 + 2], y2 = outbuf[idx * 4 + 3];
            GX1[base + pos] = x1; GY1[base + pos] = y1;
            GX2[base + pos] = x2; GY2[base + pos] = y2;
            GAR[base + pos] = (x2 - x1) * (y2 - y1);
            GIX[base + pos] = idx;
            CROW[base + pos] = c;
        }
        rank += tot;
        __syncthreads();
    }
}

// ---------------- NMS stage 2: ballot mask + nonzero-word bitmap ----------------
__launch_bounds__(256)
__global__ void nms_mask(const float* __restrict__ GX1, const float* __restrict__ GY1,
                         const float* __restrict__ GX2, const float* __restrict__ GY2,
                         const float* __restrict__ GAR,
                         const int* __restrict__ CROW,
                         const int* __restrict__ NCOUNT, const int* __restrict__ NBASE,
                         unsigned long long* __restrict__ MASK,
                         unsigned long long* __restrict__ NZ)
{
    int lane = threadIdx.x & 63, wid = threadIdx.x >> 6;
    int gr = blockIdx.x * 4 + wid;
    int tot = NBASE[79] + NCOUNT[79];
    if (gr >= tot) return;
    int c = CROW[gr];
    int base = NBASE[c], n = NCOUNT[c];
    int r = gr - base;
    float rx1 = GX1[gr], ry1 = GY1[gr];
    float rx2 = GX2[gr], ry2 = GY2[gr];
    float rar = GAR[gr];
    int Wc = (n + 63) >> 6;
    unsigned long long nz0 = 0ull, nz1 = 0ull, nz2 = 0ull;
    for (int w = 0; w < Wc; ++w) {
        int jb = w * 64;
        unsigned long long m = 0ull;
        if (jb + 63 > r) {
            int j = jb + lane;
            bool pred = false;
            if (j > r && j < n) {
                float xx1 = fmaxf(rx1, GX1[base + j]);
                float yy1 = fmaxf(ry1, GY1[base + j]);
                float xx2 = fminf(rx2, GX2[base + j]);
                float yy2 = fminf(ry2, GY2[base + j]);
                float ww = fmaxf(1e-28f, xx2 - xx1);
                float hh = fmaxf(1e-28f, yy2 - yy1);
                float inter = ww * hh;
                float ovr = inter / (rar + GAR[base + j] - inter);
                pred = (ovr > NMS_T);
            }
            m = __ballot(pred);
        }
        if (lane == 0) {
            MASK[(size_t)gr * WMAX + w] = m;
            if (m) {
                if (w < 64)       nz0 |= 1ull << w;
                else if (w < 128) nz1 |= 1ull << (w - 64);
                else              nz2 |= 1ull << (w - 128);
            }
        }
    }
    if (lane == 0) {
        NZ[(size_t)gr * 4 + 0] = nz0;
        NZ[(size_t)gr * 4 + 1] = nz1;
        NZ[(size_t)gr * 4 + 2] = nz2;
    }
}

// ---------------- NMS stage 3: ffs scan + sparse-word OR (NZ bitmap) -----------
__launch_bounds__(256)
__global__ void nms_scan(const unsigned long long* __restrict__ MASK,
                         const unsigned long long* __restrict__ NZ,
                         const int* __restrict__ GIX,
                         const int* __restrict__ NCOUNT, const int* __restrict__ NBASE,
                         float* __restrict__ keep)
{
    int c = blockIdx.x, t = threadIdx.x;
    int n = NCOUNT[c];
    if (n == 0) return;
    int base = NBASE[c];
    int Wc = (n + 63) >> 6;
    __shared__ unsigned long long remv[WMAX];
    __shared__ unsigned long long sdiag[64];
    __shared__ unsigned long long s_am;
    __shared__ int s_rows[64];
    __shared__ int s_na;
    for (int w = t; w < Wc; w += 256) remv[w] = 0ull;
    __syncthreads();
    for (int i0 = 0; i0 < n; i0 += 64) {
        int rows = min(64, n - i0);
        int wq = i0 >> 6;
        if (t < rows) sdiag[t] = MASK[(size_t)(base + i0 + t) * WMAX + wq];
        __syncthreads();
        if (t == 0) {
            unsigned long long live = (rows < 64) ? ((1ull << rows) - 1ull) : ~0ull;
            live &= ~remv[wq];
            unsigned long long am = 0ull;
            int na = 0;
            while (live) {
                int rr = __ffsll((unsigned long long)live) - 1;
                am |= 1ull << rr;
                s_rows[na++] = rr;
                live &= ~sdiag[rr];
                live &= ~(1ull << rr);
            }
            s_am = am; s_na = na;
        }
        __syncthreads();
        unsigned long long am = s_am;
        int na = s_na;
        if (t < na) {
            int gr = base + i0 + s_rows[t];
#pragma unroll
            for (int part = 0; part < 3; ++part) {
                unsigned long long nz = NZ[(size_t)gr * 4 + part];
                while (nz) {
                    int b = __ffsll((unsigned long long)nz) - 1;
                    nz &= nz - 1ull;
                    int w = part * 64 + b;
                    atomicOr(&remv[w], MASK[(size_t)gr * WMAX + w]);
                }
            }
        }
        __syncthreads();
        if (t < rows && ((am >> t) & 1ull)) keep[GIX[base + i0 + t]] = 1.0f;
        __syncthreads();
    }
}

// ---------------- host orchestration ----------------
extern "C" void kernel_launch(void* const* d_in, const int* in_sizes, int n_in,
                              void* d_out, int out_size, void* d_ws, size_t ws_size,
                              hipStream_t stream)
{
    const float* c3      = (const float*)d_in[0];
    const float* c4      = (const float*)d_in[1];
    const float* c5      = (const float*)d_in[2];
    const float* lat1_w  = (const float*)d_in[3];
    const float* lat1_b  = (const float*)d_in[4];
    const float* lat2_w  = (const float*)d_in[5];
    const float* lat2_b  = (const float*)d_in[6];
    const float* lat3_w  = (const float*)d_in[7];
    const float* lat3_b  = (const float*)d_in[8];
    const float* sm1_w   = (const float*)d_in[9];
    const float* sm1_b   = (const float*)d_in[10];
    const float* sm2_w   = (const float*)d_in[11];
    const float* sm2_b   = (const float*)d_in[12];
    const float* sm3_w   = (const float*)d_in[13];
    const float* sm3_b   = (const float*)d_in[14];
    const float* clsh_w  = (const float*)d_in[15];
    const float* clsh_b  = (const float*)d_in[16];
    const float* regh_w  = (const float*)d_in[17];
    const float* regh_b  = (const float*)d_in[18];
    const float* clsd_w  = (const float*)d_in[19];
    const float* clsd_b  = (const float*)d_in[20];
    const float* regd_w  = (const float*)d_in[21];
    const float* regd_b  = (const float*)d_in[22];
    const float* ctnd_w  = (const float*)d_in[23];
    const float* ctnd_b  = (const float*)d_in[24];

    float* ws = (float*)d_ws;
    float* T3 = ws + OFF_T3;  float* T4 = ws + OFF_T4;  float* T5 = ws + OFF_T5;
    float* P3 = ws + OFF_P3;  float* P4 = ws + OFF_P4;  float* P5 = ws + OFF_P5;
    float* HA3 = ws + OFF_HA3; float* HA4 = ws + OFF_HA4; float* HA5 = ws + OFF_HA5;
    float* HB3 = ws + OFF_HB3; float* HB4 = ws + OFF_HB4; float* HB5 = ws + OFF_HB5;
    float* HD3 = ws + OFF_HD3; float* HD4 = ws + OFF_HD4; float* HD5 = ws + OFF_HD5;
    float* CLS = ws + OFF_CLS; float* REG = ws + OFF_REG; float* CTN = ws + OFF_CTN;
    _Float16* WH = (_Float16*)(ws + OFF_W2H);
    _Float16* WL = (_Float16*)(ws + OFF_W2L);
    unsigned long long* KEYS = (unsigned long long*)(ws + POFF_KEYS);
    float* SCS = ws + POFF_SCS;
    int* CLSS = (int*)(ws + POFF_CLSS);
    int* IDXS = (int*)(ws + POFF_IDXS);
    float* GX1 = ws + POFF_GX1; float* GY1 = ws + POFF_GY1;
    float* GX2 = ws + POFF_GX2; float* GY2 = ws + POFF_GY2;
    float* GAR = ws + POFF_GAR;
    int* GIX = (int*)(ws + POFF_GIX);
    int* CROW = (int*)(ws + POFF_CROW);
    int* NCOUNT = (int*)(ws + POFF_NCNT);
    int* NBASE  = (int*)(ws + POFF_NBASE);
    unsigned long long* NZ = (unsigned long long*)(ws + POFF_NZ);
    unsigned long long* MASK = (unsigned long long*)(ws + POFF_MASK);

    float* out = (float*)d_out;
    dim3 blk(256);

    // weight f16 hi/lo prep (11 matrices, fragment-order layout)
    w2prep<<<dim3((11 * WSTEP9 + 255) / 256), blk, 0, stream>>>(
        clsh_w, regh_w, sm1_w, sm2_w, sm3_w, WH, WL);

    // FPN laterals (dependency chain), then all smooths fused (MFMA)
    conv1x1_kernel<<<dim3(7, 4), blk, 0, stream>>>(c5, lat3_w, lat3_b, T5, nullptr,
                                                   512, 256, 400, 20, 400, 0);
    conv1x1_kernel<<<dim3(25, 4), blk, 0, stream>>>(c4, lat2_w, lat2_b, T4, T5,
                                                    256, 256, 1600, 40, 1600, 0);
    conv1x1_kernel<<<dim3(100, 4), blk, 0, stream>>>(c3, lat1_w, lat1_b, T3, T4,
                                                     128, 256, 6400, 80, 6400, 0);
    {
        MC mc{};
        float* sT[3] = {T3, T4, T5};
        float* sP[3] = {P3, P4, P5};
        const float* sB[3] = {sm1_b, sm2_b, sm3_b};
        for (int l = 0; l < 3; ++l) {
            mc.src[0][l] = sT[l]; mc.dst[0][l] = sP[l];
            mc.wh[0][l] = WH + (size_t)(8 + l) * WSTEP9;
            mc.wl[0][l] = WL + (size_t)(8 + l) * WSTEP9;
            mc.bias[0][l] = sB[l];
        }
        mc.act = 0; mc.nbr = 1;
        mconv3x3<<<dim3(140 * 4), blk, 0, stream>>>(mc);
    }
    // heads: 4 MFMA layers (slice-swizzled 1D grid)
    {
        float* clsS[3][5] = { {P3, HA3, HB3, HA3, HB3},
                              {P4, HA4, HB4, HA4, HB4},
                              {P5, HA5, HB5, HA5, HB5} };
        float* regS[3][5] = { {P3, T3,  HD3, T3,  HD3},
                              {P4, T4,  HD4, T4,  HD4},
                              {P5, T5,  HD5, T5,  HD5} };
        for (int i = 0; i < 4; ++i) {
            MC mc{};
            for (int l = 0; l < 3; ++l) {
                mc.src[0][l] = clsS[l][i]; mc.dst[0][l] = clsS[l][i + 1];
                mc.src[1][l] = regS[l][i]; mc.dst[1][l] = regS[l][i + 1];
                mc.wh[0][l] = WH + (size_t)i * WSTEP9;
                mc.wl[0][l] = WL + (size_t)i * WSTEP9;
                mc.wh[1][l] = WH + (size_t)(4 + i) * WSTEP9;
                mc.wl[1][l] = WL + (size_t)(4 + i) * WSTEP9;
                mc.bias[0][l] = clsh_b + i * 256;
                mc.bias[1][l] = regh_b + i * 256;
            }
            mc.act = 1; mc.nbr = 2;
            mconv3x3<<<dim3(140 * 8), blk, 0, stream>>>(mc);
        }
    }

    // ---- detectors: all 9 (level x {cls,reg,ctn}) in one dispatch ----
    {
        Det9 d;
        const float* feats[3][2] = { {HB3, HD3}, {HB4, HD4}, {HB5, HD5} };
        int   npx[3]   = {6400, 1600, 400};
        int   obase[3] = {0, 6400, 8000};
        int q = 0, bacc = 0;
        for (int l = 0; l < 3; ++l) {
            d.src[q] = feats[l][0]; d.w[q] = clsd_w; d.b[q] = clsd_b; d.dst[q] = CLS;
            d.cout[q] = 80; d.npx[q] = npx[l]; d.obase[q] = obase[l];
            d.bstart[q] = bacc; d.npxb[q] = (npx[l] + 63) / 64;
            bacc += d.npxb[q] * 2; ++q;
            d.src[q] = feats[l][1]; d.w[q] = regd_w; d.b[q] = regd_b; d.dst[q] = REG;
            d.cout[q] = 4; d.npx[q] = npx[l]; d.obase[q] = obase[l];
            d.bstart[q] = bacc; d.npxb[q] = (npx[l] + 63) / 64;
            bacc += d.npxb[q]; ++q;
            d.src[q] = feats[l][1]; d.w[q] = ctnd_w; d.b[q] = ctnd_b; d.dst[q] = CTN;
            d.cout[q] = 1; d.npx[q] = npx[l]; d.obase[q] = obase[l];
            d.bstart[q] = bacc; d.npxb[q] = (npx[l] + 63) / 64;
            bacc += d.npxb[q]; ++q;
        }
        det1x1_fused<<<dim3(bacc), blk, 0, stream>>>(d);
    }

    // ---- decode ----
    decode_kernel<<<dim3(64), blk, 0, stream>>>(CLS, REG, CTN, out, KEYS);

    // ---- hybrid bitonic sort ----
    bitonic_local<<<dim3(8), blk, 0, stream>>>(KEYS, 0u);
    bitonic_global<<<dim3(32), blk, 0, stream>>>(KEYS, 4096u, 2048u);
    bitonic_local<<<dim3(8), blk, 0, stream>>>(KEYS, 4096u);
    bitonic_global<<<dim3(32), blk, 0, stream>>>(KEYS, 8192u, 4096u);
    bitonic_global<<<dim3(32), blk, 0, stream>>>(KEYS, 8192u, 2048u);
    bitonic_local<<<dim3(8), blk, 0, stream>>>(KEYS, 8192u);
    bitonic_global<<<dim3(32), blk, 0, stream>>>(KEYS, 16384u, 8192u);
    bitonic_global<<<dim3(32), blk, 0, stream>>>(KEYS, 16384u, 4096u);
    bitonic_global<<<dim3(32), blk, 0, stream>>>(KEYS, 16384u, 2048u);
    bitonic_local<<<dim3(8), blk, 0, stream>>>(KEYS, 16384u);

    // ---- NMS pipeline ----
    sorted_aux<<<dim3(64), blk, 0, stream>>>(KEYS, out, SCS, CLSS, IDXS);
    compact_cls<<<dim3(80), blk, 0, stream>>>(SCS, CLSS, IDXS, out,
                                              GX1, GY1, GX2, GY2, GAR, GIX, CROW,
                                              NCOUNT, NBASE);
    nms_mask<<<dim3(2100), blk, 0, stream>>>(GX1, GY1, GX2, GY2, GAR, CROW,
                                             NCOUNT, NBASE, MASK, NZ);
    nms_scan<<<dim3(80), blk, 0, stream>>>(MASK, NZ, GIX, NCOUNT, NBASE, out + 50400);
}

// Round 24
// 851.095 us; speedup vs baseline: 1.1669x; 1.1006x over previous
//
#include <hip/hip_runtime.h>
#include <stdint.h>

#define CONF_T 0.05f
#define NMS_T  0.5f
#define WMAX   132           // ceil(8400/64)
#define WSTEP9 589824        // 256*256*9

typedef _Float16 f16x8 __attribute__((ext_vector_type(8)));
typedef _Float16 f16x2 __attribute__((ext_vector_type(2)));
typedef float    f32x4 __attribute__((ext_vector_type(4)));
#define MFMA16 __builtin_amdgcn_mfma_f32_16x16x32_f16

// ---- workspace layout (float offsets) ----
#define OFF_T3   0u
#define OFF_T4   1638400u
#define OFF_T5   2048000u
#define OFF_P3   2150400u
#define OFF_P4   3788800u
#define OFF_P5   4198400u
#define OFF_HA3  4300800u
#define OFF_HA4  5939200u
#define OFF_HA5  6348800u
#define OFF_HB3  6451200u
#define OFF_HB4  8089600u
#define OFF_HB5  8499200u
#define OFF_HD3  8601600u
#define OFF_HD4  10240000u
#define OFF_HD5  10649600u
#define OFF_CLS  10752000u
#define OFF_REG  11424000u
#define OFF_CTN  11457600u
#define OFF_W2H  11466000u                 // 11 matrices x 589824 f16 (hi)
#define OFF_W2L  14710032u                 // (lo)
#define WS_NEED  17954064u
// post-processing arrays (T3 region, free after conv stack)
#define POFF_KEYS  (OFF_T3 + 0u)
#define POFF_SCS   (OFF_T3 + 32768u)
#define POFF_CLSS  (OFF_T3 + 49152u)
#define POFF_IDXS  (OFF_T3 + 65536u)
#define POFF_GX1   (OFF_T3 + 81920u)
#define POFF_GY1   (OFF_T3 + 90320u)
#define POFF_GX2   (OFF_T3 + 98720u)
#define POFF_GY2   (OFF_T3 + 107120u)
#define POFF_GAR   (OFF_T3 + 115520u)
#define POFF_GIX   (OFF_T3 + 123920u)
#define POFF_NCNT  (OFF_T3 + 132320u)
#define POFF_NBASE (OFF_T3 + 132400u)
#define POFF_CROW  (OFF_T3 + 132480u)      // 8400 ints: compacted row -> class
#define POFF_NZ    (OFF_T3 + 140880u)      // 8400 x 4 u64 nonzero-word bitmaps
#define POFF_MASK  OFF_HA3

// ---------------- conv 1x1 (+ optional nearest-up2 add) ----------------
__launch_bounds__(256)
__global__ void conv1x1_kernel(const float* __restrict__ in, const float* __restrict__ w,
                               const float* __restrict__ b, float* __restrict__ out,
                               const float* __restrict__ add,
                               int Cin, int Cout, int NPX, int W, int outStride, int outBase)
{
    __shared__ float s_in[16][64];
    __shared__ float s_w[16][64];
    int t = threadIdx.x;
    int pxg = t & 31, cg = t >> 5;
    int px0 = blockIdx.x * 64;
    int co0 = blockIdx.y * 64;
    float acc[8][2];
#pragma unroll
    for (int c = 0; c < 8; ++c) { acc[c][0] = 0.f; acc[c][1] = 0.f; }
    int chunks = Cin >> 4;
    int wco = t >> 2, wpart = t & 3;
    for (int ch = 0; ch < chunks; ++ch) {
        int ci0 = ch << 4;
#pragma unroll
        for (int k = 0; k < 4; ++k) {
            int id = t + k * 256;
            int ci = id >> 6, pp = id & 63;
            int gp = px0 + pp;
            s_in[ci][pp] = (gp < NPX) ? in[(size_t)(ci0 + ci) * NPX + gp] : 0.f;
        }
        {
            int gco = co0 + wco;
            if (gco < Cout) {
                const float* run = w + (size_t)gco * Cin + ci0;
#pragma unroll
                for (int k = 0; k < 4; ++k) {
                    int e = wpart + 4 * k;
                    s_w[e][wco] = run[e];
                }
            } else {
#pragma unroll
                for (int k = 0; k < 4; ++k) s_w[wpart + 4 * k][wco] = 0.f;
            }
        }
        __syncthreads();
#pragma unroll
        for (int ci = 0; ci < 16; ++ci) {
            float i0 = s_in[ci][pxg * 2], i1 = s_in[ci][pxg * 2 + 1];
#pragma unroll
            for (int c = 0; c < 8; ++c) {
                float wv = s_w[ci][cg * 8 + c];
                acc[c][0] += wv * i0;
                acc[c][1] += wv * i1;
            }
        }
        __syncthreads();
    }
    for (int c = 0; c < 8; ++c) {
        int co = co0 + cg * 8 + c;
        if (co >= Cout) break;
        float bb = b[co];
#pragma unroll
        for (int j = 0; j < 2; ++j) {
            int p = px0 + pxg * 2 + j;
            if (p < NPX) {
                float v = acc[c][j] + bb;
                if (add) {
                    int y = p / W, x = p % W;
                    int Sp = W >> 1;
                    v += add[(size_t)co * (Sp * Sp) + (y >> 1) * Sp + (x >> 1)];
                }
                out[(size_t)co * outStride + outBase + p] = v;
            }
        }
    }
}

// ---------------- fused detector 1x1 (9 combos in one dispatch) ----------------
struct Det9 {
    const float* src[9]; const float* w[9]; const float* b[9];
    float*       dst[9];
    int cout[9], npx[9], obase[9], bstart[9], npxb[9];
};

__launch_bounds__(256)
__global__ void det1x1_fused(Det9 d)
{
    int bid = blockIdx.x;
    int q = 0;
#pragma unroll
    for (int i = 1; i < 9; ++i) if (bid >= d.bstart[i]) q = i;
    int local = bid - d.bstart[q];
    int coIdx = local / d.npxb[q];
    int pxIdx = local - coIdx * d.npxb[q];
    const float* in = d.src[q];
    const float* w  = d.w[q];
    const float* b  = d.b[q];
    float* out = d.dst[q];
    int Cout = d.cout[q], NPX = d.npx[q], outBase = d.obase[q];

    __shared__ float s_in[16][64];
    __shared__ float s_w[16][64];
    int t = threadIdx.x;
    int pxg = t & 31, cg = t >> 5;
    int px0 = pxIdx * 64;
    int co0 = coIdx * 64;
    float acc[8][2];
#pragma unroll
    for (int c = 0; c < 8; ++c) { acc[c][0] = 0.f; acc[c][1] = 0.f; }
    int wco = t >> 2, wpart = t & 3;
    for (int ch = 0; ch < 16; ++ch) {
        int ci0 = ch << 4;
#pragma unroll
        for (int k = 0; k < 4; ++k) {
            int id = t + k * 256;
            int ci = id >> 6, pp = id & 63;
            int gp = px0 + pp;
            s_in[ci][pp] = (gp < NPX) ? in[(size_t)(ci0 + ci) * NPX + gp] : 0.f;
        }
        {
            int gco = co0 + wco;
            if (gco < Cout) {
                const float* run = w + (size_t)gco * 256 + ci0;
#pragma unroll
                for (int k = 0; k < 4; ++k) {
                    int e = wpart + 4 * k;
                    s_w[e][wco] = run[e];
                }
            } else {
#pragma unroll
                for (int k = 0; k < 4; ++k) s_w[wpart + 4 * k][wco] = 0.f;
            }
        }
        __syncthreads();
#pragma unroll
        for (int ci = 0; ci < 16; ++ci) {
            float i0 = s_in[ci][pxg * 2], i1 = s_in[ci][pxg * 2 + 1];
#pragma unroll
            for (int c = 0; c < 8; ++c) {
                float wv = s_w[ci][cg * 8 + c];
                acc[c][0] += wv * i0;
                acc[c][1] += wv * i1;
            }
        }
        __syncthreads();
    }
    for (int c = 0; c < 8; ++c) {
        int co = co0 + cg * 8 + c;
        if (co >= Cout) break;
        float bb = b[co];
#pragma unroll
        for (int j = 0; j < 2; ++j) {
            int p = px0 + pxg * 2 + j;
            if (p < NPX) out[(size_t)co * 8400 + outBase + p] = acc[c][j] + bb;
        }
    }
}

// ---------------- MFMA path: weight f16 hi/lo prep (FRAGMENT-ORDER layout) ----
__launch_bounds__(256)
__global__ void w2prep(const float* __restrict__ clsh_w, const float* __restrict__ regh_w,
                       const float* __restrict__ sm1_w, const float* __restrict__ sm2_w,
                       const float* __restrict__ sm3_w,
                       _Float16* __restrict__ WH, _Float16* __restrict__ WL)
{
    int idx = blockIdx.x * 256 + threadIdx.x;
    if (idx >= 11 * WSTEP9) return;
    int m = idx / WSTEP9, e = idx - m * WSTEP9;
    int tap = e / 65536;            // 16 cob * 8 ck * 512
    int r   = e - tap * 65536;
    int cob = r / 4096;             // 8 ck * 512
    int r2  = r - cob * 4096;
    int ck  = r2 / 512;
    int r3  = r2 - ck * 512;
    int lane = r3 / 8, el = r3 - (r3 / 8) * 8;
    int co = cob * 16 + (lane & 15);
    int ci = ck * 32 + (lane >> 4) * 8 + el;
    const float* srcb;
    if (m < 4)       srcb = clsh_w + (size_t)m * WSTEP9;
    else if (m < 8)  srcb = regh_w + (size_t)(m - 4) * WSTEP9;
    else if (m == 8) srcb = sm1_w;
    else if (m == 9) srcb = sm2_w;
    else             srcb = sm3_w;
    float f = srcb[(size_t)co * 2304 + ci * 9 + tap];
    _Float16 h = (_Float16)f;
    _Float16 l = (_Float16)(f - (float)h);
    WH[idx] = h; WL[idx] = l;
}

// ---------------- MFMA conv3x3 (fp16 3-term split; 16x2 tiles) ----------------
// 16x2 output tile per block (was 16x4): LDS 23KB (was 34.8KB) -> 6-7 blocks/CU
// by LDS; each wave owns ONE 16-co slice (wid) -> A-ring and acc halve -> lower
// VGPR. Attacks the measured latency/occupancy bound (smooth at 2.2 blk/CU ran
// at half the throughput of heads at 4.4 blk/CU -> perf ~ resident waves).
// Per-output FP order unchanged (ck -> tap -> hh,hl,lh) -> absmax identical.
struct MC {
    const float*    src[2][3];
    float*          dst[2][3];
    const _Float16* wh[2][3];
    const _Float16* wl[2][3];
    const float*    bias[2][3];
    int act;
    int nbr;
};

__launch_bounds__(256)
__global__ void mconv3x3(MC p)
{
    __shared__ __align__(16) _Float16 SH[2][72 * 40];
    __shared__ __align__(16) _Float16 SL[2][72 * 40];
    int t = threadIdx.x;
    int NS = 4 * p.nbr;
    int bid = blockIdx.x;
    int slice = bid % NS;
    int sp = bid / NS;                        // 0..279: 200 L3, 60 L4, 20 L5
    int br = slice % p.nbr;
    int co0 = (slice / p.nbr) * 64;
    int lvl = (sp < 200) ? 0 : (sp < 260) ? 1 : 2;
    int tloc = sp - ((lvl == 0) ? 0 : (lvl == 1) ? 200 : 260);
    int W = (lvl == 0) ? 80 : (lvl == 1) ? 40 : 20;
    int nTx = (lvl == 0) ? 5 : (lvl == 1) ? 3 : 2;
    int HW = W * W;
    int bx0 = (tloc % nTx) * 16, by0 = (tloc / nTx) * 2;
    const float* src = p.src[br][lvl];
    float* dst = p.dst[br][lvl];
    const _Float16* wh = p.wh[br][lvl];
    const _Float16* wl = p.wl[br][lvl];
    const float* bias = p.bias[br][lvl];

    int lane = t & 63, wid = t >> 6;
    int colc = lane & 15, g = lane >> 4;

    // staging descriptors: 1152 ci-pair slots (72 cells x 16 pairs)
    int sgo[5], sla[5];
#pragma unroll
    for (int k = 0; k < 5; ++k) {
        int s2 = t + k * 256;
        sgo[k] = -1; sla[k] = 0;
        if (s2 < 1152) {
            int ci2 = s2 / 72, cell = s2 - ci2 * 72;
            int r = cell / 18, c = cell - r * 18;
            sla[k] = cell * 40 + ci2 * 2;
            int gy = by0 - 1 + r, gx = bx0 - 1 + c;
            if (gy >= 0 && gy < W && gx >= 0 && gx < W)
                sgo[k] = (ci2 * 2) * HW + gy * W + gx;
        }
    }

    f32x4 acc[2];
    acc[0] = (f32x4)0.f; acc[1] = (f32x4)0.f;

    // stage chunk 0
#pragma unroll
    for (int k = 0; k < 5; ++k) {
        if (t + k * 256 < 1152) {
            float v0 = 0.f, v1 = 0.f;
            if (sgo[k] >= 0) { v0 = src[sgo[k]]; v1 = src[sgo[k] + HW]; }
            _Float16 h0 = (_Float16)v0, h1 = (_Float16)v1;
            _Float16 l0 = (_Float16)(v0 - (float)h0), l1 = (_Float16)(v1 - (float)h1);
            f16x2 ph = {h0, h1}, pl = {l0, l1};
            *(f16x2*)&SH[0][sla[k]] = ph;
            *(f16x2*)&SL[0][sla[k]] = pl;
        }
    }
    __syncthreads();

    int cob0 = (co0 >> 4) + wid;              // this wave's A-block
    auto aoff = [&](int ckk, int tap) -> size_t {
        return ((size_t)((tap * 16 + cob0) * 8 + ckk)) * 512 + lane * 8;
    };
    // 3-slot A-frag ring (indices compile-time after unroll)
    f16x8 Ah[3], Al[3];
    {
        size_t a0 = aoff(0, 0);
        Ah[0] = *(const f16x8*)(wh + a0); Al[0] = *(const f16x8*)(wl + a0);
        a0 = aoff(0, 1);
        Ah[1] = *(const f16x8*)(wh + a0); Al[1] = *(const f16x8*)(wl + a0);
    }
    for (int ck = 0; ck < 8; ++ck) {
        const _Float16* sh  = SH[ck & 1];
        const _Float16* sl_ = SL[ck & 1];
        float pv[10];
        bool pf = (ck < 7);
        if (pf) {
            const float* sb = src + (size_t)(ck + 1) * 32 * HW;
#pragma unroll
            for (int k = 0; k < 5; ++k) {
                pv[2 * k] = 0.f; pv[2 * k + 1] = 0.f;
                if (t + k * 256 < 1152 && sgo[k] >= 0) {
                    pv[2 * k] = sb[sgo[k]]; pv[2 * k + 1] = sb[sgo[k] + HW];
                }
            }
        }
#pragma unroll
        for (int tap = 0; tap < 9; ++tap) {
            int ky = tap / 3, kx = tap - ky * 3;
            int slot = tap % 3;
            int nsl  = (tap + 2) % 3;
            int pck = ck, ptap = tap + 2;
            if (ptap >= 9) { ptap -= 9; if (pf) pck = ck + 1; }
            size_t an = aoff(pck, ptap);
            Ah[nsl] = *(const f16x8*)(wh + an);
            Al[nsl] = *(const f16x8*)(wl + an);
#pragma unroll
            for (int ny = 0; ny < 2; ++ny) {
                int cell = (ny + ky) * 18 + colc + kx;
                f16x8 bh = *(const f16x8*)(sh  + cell * 40 + g * 8);
                f16x8 bl = *(const f16x8*)(sl_ + cell * 40 + g * 8);
                acc[ny] = MFMA16(Ah[slot], bh, acc[ny], 0, 0, 0);
                acc[ny] = MFMA16(Ah[slot], bl, acc[ny], 0, 0, 0);
                acc[ny] = MFMA16(Al[slot], bh, acc[ny], 0, 0, 0);
            }
        }
        if (pf) {
            _Float16* nh = SH[(ck + 1) & 1];
            _Float16* nl = SL[(ck + 1) & 1];
#pragma unroll
            for (int k = 0; k < 5; ++k) {
                if (t + k * 256 < 1152) {
                    float v0 = pv[2 * k], v1 = pv[2 * k + 1];
                    _Float16 h0 = (_Float16)v0, h1 = (_Float16)v1;
                    _Float16 l0 = (_Float16)(v0 - (float)h0), l1 = (_Float16)(v1 - (float)h1);
                    f16x2 ph = {h0, h1}, pl = {l0, l1};
                    *(f16x2*)&nh[sla[k]] = ph;
                    *(f16x2*)&nl[sla[k]] = pl;
                }
            }
        }
        __syncthreads();
    }

    int x = bx0 + colc;
    if (x < W) {
        int cob = co0 + wid * 16 + g * 4;
#pragma unroll
        for (int ny = 0; ny < 2; ++ny) {
            int y = by0 + ny;
#pragma unroll
            for (int i = 0; i < 4; ++i) {
                int co = cob + i;
                float v = acc[ny][i] + bias[co];
                if (p.act) v = (v >= 0.f) ? v : 0.1f * v;
                dst[(size_t)co * HW + y * W + x] = v;
            }
        }
    }
}

// ---------------- decode: scores, argmax, boxes, sort keys ----------------
__launch_bounds__(256)
__global__ void decode_kernel(const float* __restrict__ cls, const float* __restrict__ reg,
                              const float* __restrict__ ctn, float* __restrict__ out,
                              unsigned long long* __restrict__ keys)
{
    int p = blockIdx.x * 256 + threadIdx.x;
    if (p >= 16384) return;
    if (p >= 8400) { keys[p] = ~0ull; return; }
    int base, hs; float s;
    if (p < 6400)      { base = 0;    hs = 80; s = 8.f;  }
    else if (p < 8000) { base = 6400; hs = 40; s = 16.f; }
    else               { base = 8000; hs = 20; s = 32.f; }
    int local = p - base;
    float gx = (float)(local % hs), gy = (float)(local / hs);
    float ct = ctn[p];
    float sct = 1.f / (1.f + expf(-ct));
    float best = -1.f; int arg = 0;
    for (int c = 0; c < 80; ++c) {
        float v = cls[(size_t)c * 8400 + p];
        float sv = 1.f / (1.f + expf(-v));
        float sc = sqrtf(sv * sct);
        if (sc > best) { best = sc; arg = c; }
    }
    float r0 = reg[0 * 8400 + p], r1 = reg[1 * 8400 + p];
    float r2 = reg[2 * 8400 + p], r3 = reg[3 * 8400 + p];
    float x1 = (gx - expf(r0)) * s / 640.f;
    float y1 = (gy - expf(r1)) * s / 640.f;
    float x2 = (gx + expf(r2)) * s / 640.f;
    float y2 = (gy + expf(r3)) * s / 640.f;
    x1 = fminf(fmaxf(x1, 0.f), 1.f);
    y1 = fminf(fmaxf(y1, 0.f), 1.f);
    x2 = fminf(fmaxf(x2, 0.f), 1.f);
    y2 = fminf(fmaxf(y2, 0.f), 1.f);
    out[p * 4 + 0] = x1; out[p * 4 + 1] = y1;
    out[p * 4 + 2] = x2; out[p * 4 + 3] = y2;
    out[33600 + p] = best;
    out[42000 + p] = (float)arg;
    out[50400 + p] = 0.f;
    unsigned int ub = __float_as_uint(best);
    keys[p] = ((unsigned long long)(~ub) << 32) | (unsigned int)p;
}

// ---------------- hybrid bitonic sort of 16384 u64 keys ----------------
__launch_bounds__(256)
__global__ void bitonic_local(unsigned long long* __restrict__ keys, unsigned kmerge)
{
    __shared__ unsigned long long sk[2048];
    int t = threadIdx.x;
    unsigned base = blockIdx.x * 2048u;
#pragma unroll
    for (int m = 0; m < 8; ++m) sk[t + m * 256] = keys[base + t + m * 256];
    __syncthreads();
    if (kmerge == 0u) {
        for (unsigned k = 2; k <= 2048u; k <<= 1) {
            for (unsigned j = k >> 1; j > 0; j >>= 1) {
#pragma unroll
                for (int pp = 0; pp < 4; ++pp) {
                    unsigned p = (unsigned)t + pp * 256u;
                    unsigned li = ((p & ~(j - 1)) << 1) | (p & (j - 1));
                    unsigned gi = base + li;
                    bool up = ((gi & k) == 0);
                    unsigned long long a = sk[li], b = sk[li + j];
                    if ((a > b) == up) { sk[li] = b; sk[li + j] = a; }
                }
                __syncthreads();
            }
        }
    } else {
        unsigned k = kmerge;
        for (unsigned j = 1024; j > 0; j >>= 1) {
#pragma unroll
            for (int pp = 0; pp < 4; ++pp) {
                unsigned p = (unsigned)t + pp * 256u;
                unsigned li = ((p & ~(j - 1)) << 1) | (p & (j - 1));
                unsigned gi = base + li;
                bool up = ((gi & k) == 0);
                unsigned long long a = sk[li], b = sk[li + j];
                if ((a > b) == up) { sk[li] = b; sk[li + j] = a; }
            }
            __syncthreads();
        }
    }
#pragma unroll
    for (int m = 0; m < 8; ++m) keys[base + t + m * 256] = sk[t + m * 256];
}

__launch_bounds__(256)
__global__ void bitonic_global(unsigned long long* __restrict__ keys, unsigned k, unsigned j)
{
    unsigned p = blockIdx.x * 256u + threadIdx.x;
    unsigned i = ((p & ~(j - 1)) << 1) | (p & (j - 1));
    bool up = ((i & k) == 0);
    unsigned long long a = keys[i], b = keys[i + j];
    if ((a > b) == up) { keys[i] = b; keys[i + j] = a; }
}

// ---------------- expand sorted keys into SoA arrays ----------------
__launch_bounds__(256)
__global__ void sorted_aux(const unsigned long long* __restrict__ keys,
                           const float* __restrict__ out,
                           float* __restrict__ scs, int* __restrict__ clss,
                           int* __restrict__ idxs)
{
    int i = blockIdx.x * 256 + threadIdx.x;
    if (i >= 16384) return;
    unsigned long long key = keys[i];
    unsigned ub = ~(unsigned)(key >> 32);
    float sc = __uint_as_float(ub);
    unsigned idx = (unsigned)(key & 0xffffffffu);
    int cl = -1;
    if (idx < 8400u) cl = (int)out[42000 + idx];
    else sc = 0.f;
    scs[i] = sc; clss[i] = cl; idxs[i] = (int)idx;
}

// ---------------- NMS stage 1: per-class stable compaction (+ row->class map) ----
__launch_bounds__(256)
__global__ void compact_cls(const float* __restrict__ scs, const int* __restrict__ clss,
                            const int* __restrict__ idxs, const float* __restrict__ outbuf,
                            float* __restrict__ GX1, float* __restrict__ GY1,
                            float* __restrict__ GX2, float* __restrict__ GY2,
                            float* __restrict__ GAR, int* __restrict__ GIX,
                            int* __restrict__ CROW,
                            int* __restrict__ NCOUNT, int* __restrict__ NBASE)
{
    int c = blockIdx.x, t = threadIdx.x;
    __shared__ int s_red[2];
    __shared__ int s_wtot[4];
    int cb = 0, co = 0;
    for (int i = t; i < 16384; i += 256) {
        float sc = scs[i]; int cl = clss[i];
        if (sc >= CONF_T && cl >= 0) { cb += (cl < c); co += (cl == c); }
    }
    if (t == 0) { s_red[0] = 0; s_red[1] = 0; }
    __syncthreads();
    atomicAdd(&s_red[0], cb);
    atomicAdd(&s_red[1], co);
    __syncthreads();
    int base = s_red[0], n = s_red[1];
    if (t == 0) { NCOUNT[c] = n; NBASE[c] = base; }

    int rank = 0;
    for (int st = 0; st < 16384; st += 256) {
        int i = st + t;
        float sc = scs[i]; int cl = clss[i];
        bool flag = (sc >= CONF_T && cl == c);
        unsigned long long m = __ballot(flag);
        int lane = t & 63, wv = t >> 6;
        if (lane == 0) s_wtot[wv] = __popcll(m);
        __syncthreads();
        int off = rank;
        for (int w = 0; w < wv; ++w) off += s_wtot[w];
        int tot = s_wtot[0] + s_wtot[1] + s_wtot[2] + s_wtot[3];
        if (flag) {
            int pos = off + __popcll(m & ((1ull << lane) - 1ull));
            int idx = idxs[i];
            float x1 = outbuf[idx * 4 + 0], y1 = outbuf[idx * 4 + 1];
            float x2 = outbuf[idx * 4 + 2], y2 = outbuf[idx * 4 + 3];
            GX1[base + pos] = x1; GY1[base + pos] = y1;
            GX2[base + pos] = x2; GY2[base + pos] = y2;
            GAR[base + pos] = (x2 - x1) * (y2 - y1);
            GIX[base + pos] = idx;
            CROW[base + pos] = c;
        }
        rank += tot;
        __syncthreads();
    }
}

// ---------------- NMS stage 2: ballot mask + nonzero-word bitmap ----------------
__launch_bounds__(256)
__global__ void nms_mask(const float* __restrict__ GX1, const float* __restrict__ GY1,
                         const float* __restrict__ GX2, const float* __restrict__ GY2,
                         const float* __restrict__ GAR,
                         const int* __restrict__ CROW,
                         const int* __restrict__ NCOUNT, const int* __restrict__ NBASE,
                         unsigned long long* __restrict__ MASK,
                         unsigned long long* __restrict__ NZ)
{
    int lane = threadIdx.x & 63, wid = threadIdx.x >> 6;
    int gr = blockIdx.x * 4 + wid;
    int tot = NBASE[79] + NCOUNT[79];
    if (gr >= tot) return;
    int c = CROW[gr];
    int base = NBASE[c], n = NCOUNT[c];
    int r = gr - base;
    float rx1 = GX1[gr], ry1 = GY1[gr];
    float rx2 = GX2[gr], ry2 = GY2[gr];
    float rar = GAR[gr];
    int Wc = (n + 63) >> 6;
    unsigned long long nz0 = 0ull, nz1 = 0ull, nz2 = 0ull;
    for (int w = 0; w < Wc; ++w) {
        int jb = w * 64;
        unsigned long long m = 0ull;
        if (jb + 63 > r) {
            int j = jb + lane;
            bool pred = false;
            if (j > r && j < n) {
                float xx1 = fmaxf(rx1, GX1[base + j]);
                float yy1 = fmaxf(ry1, GY1[base + j]);
                float xx2 = fminf(rx2, GX2[base + j]);
                float yy2 = fminf(ry2, GY2[base + j]);
                float ww = fmaxf(1e-28f, xx2 - xx1);
                float hh = fmaxf(1e-28f, yy2 - yy1);
                float inter = ww * hh;
                float ovr = inter / (rar + GAR[base + j] - inter);
                pred = (ovr > NMS_T);
            }
            m = __ballot(pred);
        }
        if (lane == 0) {
            MASK[(size_t)gr * WMAX + w] = m;
            if (m) {
                if (w < 64)       nz0 |= 1ull << w;
                else if (w < 128) nz1 |= 1ull << (w - 64);
                else              nz2 |= 1ull << (w - 128);
            }
        }
    }
    if (lane == 0) {
        NZ[(size_t)gr * 4 + 0] = nz0;
        NZ[(size_t)gr * 4 + 1] = nz1;
        NZ[(size_t)gr * 4 + 2] = nz2;
    }
}

// ---------------- NMS stage 3: ffs scan + sparse-word OR (NZ bitmap) -----------
__launch_bounds__(256)
__global__ void nms_scan(const unsigned long long* __restrict__ MASK,
                         const unsigned long long* __restrict__ NZ,
                         const int* __restrict__ GIX,
                         const int* __restrict__ NCOUNT, const int* __restrict__ NBASE,
                         float* __restrict__ keep)
{
    int c = blockIdx.x, t = threadIdx.x;
    int n = NCOUNT[c];
    if (n == 0) return;
    int base = NBASE[c];
    int Wc = (n + 63) >> 6;
    __shared__ unsigned long long remv[WMAX];
    __shared__ unsigned long long sdiag[64];
    __shared__ unsigned long long s_am;
    __shared__ int s_rows[64];
    __shared__ int s_na;
    for (int w = t; w < Wc; w += 256) remv[w] = 0ull;
    __syncthreads();
    for (int i0 = 0; i0 < n; i0 += 64) {
        int rows = min(64, n - i0);
        int wq = i0 >> 6;
        if (t < rows) sdiag[t] = MASK[(size_t)(base + i0 + t) * WMAX + wq];
        __syncthreads();
        if (t == 0) {
            unsigned long long live = (rows < 64) ? ((1ull << rows) - 1ull) : ~0ull;
            live &= ~remv[wq];
            unsigned long long am = 0ull;
            int na = 0;
            while (live) {
                int rr = __ffsll((unsigned long long)live) - 1;
                am |= 1ull << rr;
                s_rows[na++] = rr;
                live &= ~sdiag[rr];
                live &= ~(1ull << rr);
            }
            s_am = am; s_na = na;
        }
        __syncthreads();
        unsigned long long am = s_am;
        int na = s_na;
        if (t < na) {
            int gr = base + i0 + s_rows[t];
#pragma unroll
            for (int part = 0; part < 3; ++part) {
                unsigned long long nz = NZ[(size_t)gr * 4 + part];
                while (nz) {
                    int b = __ffsll((unsigned long long)nz) - 1;
                    nz &= nz - 1ull;
                    int w = part * 64 + b;
                    atomicOr(&remv[w], MASK[(size_t)gr * WMAX + w]);
                }
            }
        }
        __syncthreads();
        if (t < rows && ((am >> t) & 1ull)) keep[GIX[base + i0 + t]] = 1.0f;
        __syncthreads();
    }
}

// ---------------- host orchestration ----------------
extern "C" void kernel_launch(void* const* d_in, const int* in_sizes, int n_in,
                              void* d_out, int out_size, void* d_ws, size_t ws_size,
                              hipStream_t stream)
{
    const float* c3      = (const float*)d_in[0];
    const float* c4      = (const float*)d_in[1];
    const float* c5      = (const float*)d_in[2];
    const float* lat1_w  = (const float*)d_in[3];
    const float* lat1_b  = (const float*)d_in[4];
    const float* lat2_w  = (const float*)d_in[5];
    const float* lat2_b  = (const float*)d_in[6];
    const float* lat3_w  = (const float*)d_in[7];
    const float* lat3_b  = (const float*)d_in[8];
    const float* sm1_w   = (const float*)d_in[9];
    const float* sm1_b   = (const float*)d_in[10];
    const float* sm2_w   = (const float*)d_in[11];
    const float* sm2_b   = (const float*)d_in[12];
    const float* sm3_w   = (const float*)d_in[13];
    const float* sm3_b   = (const float*)d_in[14];
    const float* clsh_w  = (const float*)d_in[15];
    const float* clsh_b  = (const float*)d_in[16];
    const float* regh_w  = (const float*)d_in[17];
    const float* regh_b  = (const float*)d_in[18];
    const float* clsd_w  = (const float*)d_in[19];
    const float* clsd_b  = (const float*)d_in[20];
    const float* regd_w  = (const float*)d_in[21];
    const float* regd_b  = (const float*)d_in[22];
    const float* ctnd_w  = (const float*)d_in[23];
    const float* ctnd_b  = (const float*)d_in[24];

    float* ws = (float*)d_ws;
    float* T3 = ws + OFF_T3;  float* T4 = ws + OFF_T4;  float* T5 = ws + OFF_T5;
    float* P3 = ws + OFF_P3;  float* P4 = ws + OFF_P4;  float* P5 = ws + OFF_P5;
    float* HA3 = ws + OFF_HA3; float* HA4 = ws + OFF_HA4; float* HA5 = ws + OFF_HA5;
    float* HB3 = ws + OFF_HB3; float* HB4 = ws + OFF_HB4; float* HB5 = ws + OFF_HB5;
    float* HD3 = ws + OFF_HD3; float* HD4 = ws + OFF_HD4; float* HD5 = ws + OFF_HD5;
    float* CLS = ws + OFF_CLS; float* REG = ws + OFF_REG; float* CTN = ws + OFF_CTN;
    _Float16* WH = (_Float16*)(ws + OFF_W2H);
    _Float16* WL = (_Float16*)(ws + OFF_W2L);
    unsigned long long* KEYS = (unsigned long long*)(ws + POFF_KEYS);
    float* SCS = ws + POFF_SCS;
    int* CLSS = (int*)(ws + POFF_CLSS);
    int* IDXS = (int*)(ws + POFF_IDXS);
    float* GX1 = ws + POFF_GX1; float* GY1 = ws + POFF_GY1;
    float* GX2 = ws + POFF_GX2; float* GY2 = ws + POFF_GY2;
    float* GAR = ws + POFF_GAR;
    int* GIX = (int*)(ws + POFF_GIX);
    int* CROW = (int*)(ws + POFF_CROW);
    int* NCOUNT = (int*)(ws + POFF_NCNT);
    int* NBASE  = (int*)(ws + POFF_NBASE);
    unsigned long long* NZ = (unsigned long long*)(ws + POFF_NZ);
    unsigned long long* MASK = (unsigned long long*)(ws + POFF_MASK);

    float* out = (float*)d_out;
    dim3 blk(256);

    // weight f16 hi/lo prep (11 matrices, fragment-order layout)
    w2prep<<<dim3((11 * WSTEP9 + 255) / 256), blk, 0, stream>>>(
        clsh_w, regh_w, sm1_w, sm2_w, sm3_w, WH, WL);

    // FPN laterals (dependency chain), then all smooths fused (MFMA)
    conv1x1_kernel<<<dim3(7, 4), blk, 0, stream>>>(c5, lat3_w, lat3_b, T5, nullptr,
                                                   512, 256, 400, 20, 400, 0);
    conv1x1_kernel<<<dim3(25, 4), blk, 0, stream>>>(c4, lat2_w, lat2_b, T4, T5,
                                                    256, 256, 1600, 40, 1600, 0);
    conv1x1_kernel<<<dim3(100, 4), blk, 0, stream>>>(c3, lat1_w, lat1_b, T3, T4,
                                                     128, 256, 6400, 80, 6400, 0);
    {
        MC mc{};
        float* sT[3] = {T3, T4, T5};
        float* sP[3] = {P3, P4, P5};
        const float* sB[3] = {sm1_b, sm2_b, sm3_b};
        for (int l = 0; l < 3; ++l) {
            mc.src[0][l] = sT[l]; mc.dst[0][l] = sP[l];
            mc.wh[0][l] = WH + (size_t)(8 + l) * WSTEP9;
            mc.wl[0][l] = WL + (size_t)(8 + l) * WSTEP9;
            mc.bias[0][l] = sB[l];
        }
        mc.act = 0; mc.nbr = 1;
        mconv3x3<<<dim3(280 * 4), blk, 0, stream>>>(mc);
    }
    // heads: 4 MFMA layers (slice-swizzled 1D grid)
    {
        float* clsS[3][5] = { {P3, HA3, HB3, HA3, HB3},
                              {P4, HA4, HB4, HA4, HB4},
                              {P5, HA5, HB5, HA5, HB5} };
        float* regS[3][5] = { {P3, T3,  HD3, T3,  HD3},
                              {P4, T4,  HD4, T4,  HD4},
                              {P5, T5,  HD5, T5,  HD5} };
        for (int i = 0; i < 4; ++i) {
            MC mc{};
            for (int l = 0; l < 3; ++l) {
                mc.src[0][l] = clsS[l][i]; mc.dst[0][l] = clsS[l][i + 1];
                mc.src[1][l] = regS[l][i]; mc.dst[1][l] = regS[l][i + 1];
                mc.wh[0][l] = WH + (size_t)i * WSTEP9;
                mc.wl[0][l] = WL + (size_t)i * WSTEP9;
                mc.wh[1][l] = WH + (size_t)(4 + i) * WSTEP9;
                mc.wl[1][l] = WL + (size_t)(4 + i) * WSTEP9;
                mc.bias[0][l] = clsh_b + i * 256;
                mc.bias[1][l] = regh_b + i * 256;
            }
            mc.act = 1; mc.nbr = 2;
            mconv3x3<<<dim3(280 * 8), blk, 0, stream>>>(mc);
        }
    }

    // ---- detectors: all 9 (level x {cls,reg,ctn}) in one dispatch ----
    {
        Det9 d;
        const float* feats[3][2] = { {HB3, HD3}, {HB4, HD4}, {HB5, HD5} };
        int   npx[3]   = {6400, 1600, 400};
        int   obase[3] = {0, 6400, 8000};
        int q = 0, bacc = 0;
        for (int l = 0; l < 3; ++l) {
            d.src[q] = feats[l][0]; d.w[q] = clsd_w; d.b[q] = clsd_b; d.dst[q] = CLS;
            d.cout[q] = 80; d.npx[q] = npx[l]; d.obase[q] = obase[l];
            d.bstart[q] = bacc; d.npxb[q] = (npx[l] + 63) / 64;
            bacc += d.npxb[q] * 2; ++q;
            d.src[q] = feats[l][1]; d.w[q] = regd_w; d.b[q] = regd_b; d.dst[q] = REG;
            d.cout[q] = 4; d.npx[q] = npx[l]; d.obase[q] = obase[l];
            d.bstart[q] = bacc; d.npxb[q] = (npx[l] + 63) / 64;
            bacc += d.npxb[q]; ++q;
            d.src[q] = feats[l][1]; d.w[q] = ctnd_w; d.b[q] = ctnd_b; d.dst[q] = CTN;
            d.cout[q] = 1; d.npx[q] = npx[l]; d.obase[q] = obase[l];
            d.bstart[q] = bacc; d.npxb[q] = (npx[l] + 63) / 64;
            bacc += d.npxb[q]; ++q;
        }
        det1x1_fused<<<dim3(bacc), blk, 0, stream>>>(d);
    }

    // ---- decode ----
    decode_kernel<<<dim3(64), blk, 0, stream>>>(CLS, REG, CTN, out, KEYS);

    // ---- hybrid bitonic sort ----
    bitonic_local<<<dim3(8), blk, 0, stream>>>(KEYS, 0u);
    bitonic_global<<<dim3(32), blk, 0, stream>>>(KEYS, 4096u, 2048u);
    bitonic_local<<<dim3(8), blk, 0, stream>>>(KEYS, 4096u);
    bitonic_global<<<dim3(32), blk, 0, stream>>>(KEYS, 8192u, 4096u);
    bitonic_global<<<dim3(32), blk, 0, stream>>>(KEYS, 8192u, 2048u);
    bitonic_local<<<dim3(8), blk, 0, stream>>>(KEYS, 8192u);
    bitonic_global<<<dim3(32), blk, 0, stream>>>(KEYS, 16384u, 8192u);
    bitonic_global<<<dim3(32), blk, 0, stream>>>(KEYS, 16384u, 4096u);
    bitonic_global<<<dim3(32), blk, 0, stream>>>(KEYS, 16384u, 2048u);
    bitonic_local<<<dim3(8), blk, 0, stream>>>(KEYS, 16384u);

    // ---- NMS pipeline ----
    sorted_aux<<<dim3(64), blk, 0, stream>>>(KEYS, out, SCS, CLSS, IDXS);
    compact_cls<<<dim3(80), blk, 0, stream>>>(SCS, CLSS, IDXS, out,
                                              GX1, GY1, GX2, GY2, GAR, GIX, CROW,
                                              NCOUNT, NBASE);
    nms_mask<<<dim3(2100), blk, 0, stream>>>(GX1, GY1, GX2, GY2, GAR, CROW,
                                             NCOUNT, NBASE, MASK, NZ);
    nms_scan<<<dim3(80), blk, 0, stream>>>(MASK, NZ, GIX, NCOUNT, NBASE, out + 50400);
}